// Round 9
// baseline (473.989 us; speedup 1.0000x reference)
//
#include <hip/hip_runtime.h>

typedef unsigned short u16;
typedef unsigned int u32;
using short8 = __attribute__((ext_vector_type(8))) short;
using f32x4  = __attribute__((ext_vector_type(4))) float;
using u32x4  = __attribute__((ext_vector_type(4))) u32;

#define N_CNT 50000
#define E_CNT 800000
#define EB_CNT 400000   // edges per batch (2 batches)

__device__ __forceinline__ u16 f2bf(float f) {
  u32 u = __builtin_bit_cast(u32, f);
  u += 0x7fffu + ((u >> 16) & 1u);
  return (u16)(u >> 16);
}
__device__ __forceinline__ float bf2f(u16 v) {
  u32 u = ((u32)v) << 16;
  return __builtin_bit_cast(float, u);
}
__device__ __forceinline__ short8 pack8(f32x4 v0, f32x4 v1) {
  short8 r;
#pragma unroll
  for (int j = 0; j < 4; ++j) r[j] = (short)f2bf(v0[j]);
#pragma unroll
  for (int j = 0; j < 4; ++j) r[4 + j] = (short)f2bf(v1[j]);
  return r;
}
__device__ __forceinline__ float siluf(float v) {
  return __fdividef(v, 1.f + __expf(-v));
}

// ---------------- prep: weight fragments (MFMA B layout) ----------------
// frag element (tile t, kstep s, lane l, i): B[k=32s+8*(l>>4)+i][n=16t+(l&15)]
// wef:   w1tail [0,4096) | w2f [4096,20480) | wc1f [20480,36864)   (u16 idx)
// w1abf: 32768 u16   (K=128 -> N=256: [W1a | W1b], 16t x 4s)
// wnf:   wn1f 32768 | wn2f 16384
__global__ void k_wf(const float* __restrict__ w1, const float* __restrict__ w2,
                     const float* __restrict__ wc1, const float* __restrict__ wn1,
                     const float* __restrict__ wn2,
                     u16* __restrict__ wef, u16* __restrict__ w1abf,
                     u16* __restrict__ wnf) {
  int idx = blockIdx.x * 256 + threadIdx.x;     // 464*256 == 118784 exact
  int i = idx & 7, l = (idx >> 3) & 63;
  int kb = 8 * (l >> 4) + i;
  int n16 = l & 15;
  if (idx < 4096) {                             // w1tail: 8t x 1s, k = 256..287 of W1
    int t = idx >> 9;
    int k = kb, n = 16 * t + n16;
    wef[idx] = (k < 17) ? f2bf(w1[(256 + k) * 128 + n]) : (u16)0;
  } else if (idx < 20480) {                     // w2f: 8t x 4s
    int u = idx - 4096, rest = u >> 9;
    int s = rest & 3, t = rest >> 2;
    wef[idx] = f2bf(w2[(32 * s + kb) * 128 + 16 * t + n16]);
  } else if (idx < 36864) {                     // wc1f: 8t x 4s
    int u = idx - 20480, rest = u >> 9;
    int s = rest & 3, t = rest >> 2;
    wef[idx] = f2bf(wc1[(32 * s + kb) * 128 + 16 * t + n16]);
  } else if (idx < 69632) {                     // w1abf: 16t x 4s, K=128, N=256
    int u = idx - 36864, rest = u >> 9;
    int s = rest & 3, t = rest >> 2;
    int k = 32 * s + kb, n = 16 * t + n16;
    float v = (n < 128) ? w1[k * 128 + n] : w1[(128 + k) * 128 + (n - 128)];
    w1abf[u] = f2bf(v);
  } else if (idx < 102400) {                    // wn1f: 8t x 8s (K=256)
    int u = idx - 69632, rest = u >> 9;
    int s = rest & 7, t = rest >> 3;
    wnf[u] = f2bf(wn1[(32 * s + kb) * 128 + 16 * t + n16]);
  } else if (idx < 118784) {                    // wn2f: 8t x 4s
    int u = idx - 102400, rest = u >> 9;
    int s = rest & 3, t = rest >> 2;
    wnf[32768 + u] = f2bf(wn2[(32 * s + kb) * 128 + 16 * t + n16]);
  }
}

// ---------------- hp = h @ [W1a|W1b] + [b1|0]  (bf16 [N][256]) ----------------
__global__ __launch_bounds__(256)
void k_hp(const float* __restrict__ h, const u16* __restrict__ w1abf,
          const float* __restrict__ b1v, u16* __restrict__ hp) {
  extern __shared__ char smem[];
  u16* wl = (u16*)smem;
  const int tid = threadIdx.x;
  {
    const u32x4* src = reinterpret_cast<const u32x4*>(w1abf);
    u32x4* dst = reinterpret_cast<u32x4*>(smem);
    for (int i2 = tid; i2 < 4096; i2 += 256) dst[i2] = src[i2];
  }
  __syncthreads();
  const int w = tid >> 6, lane = tid & 63;
  const int g = lane >> 4, c15 = lane & 15;
  float b1r[8];
#pragma unroll
  for (int t = 0; t < 8; ++t) b1r[t] = b1v[t * 16 + c15];

  int wt = blockIdx.x * 4 + w;                   // 782*4 = 3128 >= 3125
  if (wt >= 3125) return;
  int nbase = wt * 16;
  int nr = nbase + c15;
  short8 af[4];
#pragma unroll
  for (int s = 0; s < 4; ++s) {
    const float* p = h + nr * 128 + s * 32 + g * 8;
    af[s] = pack8(*reinterpret_cast<const f32x4*>(p),
                  *reinterpret_cast<const f32x4*>(p + 4));
  }
  f32x4 acc[16];
#pragma unroll
  for (int t = 0; t < 16; ++t) acc[t] = (f32x4){0.f, 0.f, 0.f, 0.f};
#pragma unroll
  for (int s = 0; s < 4; ++s) {
#pragma unroll
    for (int t = 0; t < 16; ++t) {
      short8 bf = *reinterpret_cast<const short8*>(wl + ((t * 4 + s) * 64 + lane) * 8);
      acc[t] = __builtin_amdgcn_mfma_f32_16x16x32_bf16(af[s], bf, acc[t], 0, 0, 0);
    }
  }
#pragma unroll
  for (int t = 0; t < 16; ++t) {
    float bb = (t < 8) ? b1r[t] : 0.f;
    int col = t * 16 + c15;
#pragma unroll
    for (int i = 0; i < 4; ++i)
      hp[(size_t)(nbase + g * 4 + i) * 256 + col] = f2bf(acc[t][i] + bb);
  }
}

// ---------------- CSR build (per-batch) ----------------
__global__ void k_deg(const int* __restrict__ eidx, int* __restrict__ degs) {
  int e = blockIdx.x * 256 + threadIdx.x;       // 3125*256 == 800000
  int b = (e >= EB_CNT) ? 1 : 0;
  atomicAdd(&degs[b * N_CNT + eidx[e]], 1);
}

__global__ void k_bsum(const int* __restrict__ degs, int* __restrict__ bsum) {
  int bid = blockIdx.x;                          // 196 = 2 batches x 98 chunks
  int batch = bid / 98, chunk = bid % 98;
  const int* deg = degs + batch * N_CNT;
  int b0 = chunk * 512 + threadIdx.x;
  int b1 = b0 + 256;
  int v = ((b0 < N_CNT) ? deg[b0] : 0) + ((b1 < N_CNT) ? deg[b1] : 0);
#pragma unroll
  for (int m = 1; m <= 32; m <<= 1) v += __shfl_xor(v, m, 64);
  __shared__ int ws[4];
  if ((threadIdx.x & 63) == 0) ws[threadIdx.x >> 6] = v;
  __syncthreads();
  if (threadIdx.x == 0) bsum[bid] = ws[0] + ws[1] + ws[2] + ws[3];
}

__global__ void k_mid(const int* __restrict__ bsum, int* __restrict__ boff,
                      int* __restrict__ rps) {
  int wv = threadIdx.x >> 6, lane = threadIdx.x & 63;
  if (wv >= 2) return;
  const int* bs = bsum + wv * 98;
  int* bo = boff + wv * 98;
  int carry = 0;
  for (int base = 0; base < 98; base += 64) {
    int idx = base + lane;
    int v = (idx < 98) ? bs[idx] : 0;
    int inc = v;
#pragma unroll
    for (int d = 1; d <= 32; d <<= 1) {
      int u = __shfl_up(inc, d, 64);
      if (lane >= d) inc += u;
    }
    if (idx < 98) bo[idx] = carry + inc - v;
    carry += __shfl(inc, 63, 64);
  }
  if (lane == 0) rps[wv * (N_CNT + 1) + N_CNT] = EB_CNT;
}

__global__ void k_rp(const int* __restrict__ degs, const int* __restrict__ boff,
                     int* __restrict__ rps) {
  int bid = blockIdx.x;
  int batch = bid / 98, chunk = bid % 98;
  const int* deg = degs + batch * N_CNT;
  int* rp = rps + batch * (N_CNT + 1);
  int i0 = chunk * 512 + 2 * threadIdx.x, i1 = i0 + 1;
  int a = (i0 < N_CNT) ? deg[i0] : 0;
  int b = (i1 < N_CNT) ? deg[i1] : 0;
  int s = a + b, lane = threadIdx.x & 63, wv = threadIdx.x >> 6;
  int inc = s;
#pragma unroll
  for (int d = 1; d <= 32; d <<= 1) {
    int u = __shfl_up(inc, d, 64);
    if (lane >= d) inc += u;
  }
  __shared__ int ws2[4];
  if (lane == 63) ws2[wv] = inc;
  __syncthreads();
  int woff = 0;
  for (int k = 0; k < wv; ++k) woff += ws2[k];
  int excl = boff[bid] + woff + inc - s;
  if (i0 < N_CNT) rp[i0] = excl;
  if (i1 < N_CNT) rp[i1] = excl + a;
}

__global__ void k_scatter(const int* __restrict__ eidx, const int* __restrict__ rps,
                          int* __restrict__ curs, int* __restrict__ pos) {
  int e = blockIdx.x * 256 + threadIdx.x;
  int b = (e >= EB_CNT) ? 1 : 0;
  int r = eidx[e];
  int p = atomicAdd(&curs[b * N_CNT + r], 1);
  pos[e] = rps[b * (N_CNT + 1) + r] + p;
}

// ---------------- edge kernel (round-6 math + T14 next-tile prefetch) ----------------
// 1024 thr = 16 waves, 16 edges/wave. LDS identical to round 6: w1tf 8192 | w2f 32768 |
// wc1f 32768 | atail 16x1024 | mbuf 16x4352 = 159744 B.
__global__ __launch_bounds__(1024, 4)
void egnn_edge6(const u16* __restrict__ hp, const float* __restrict__ xc,
                const float* __restrict__ ea, const int* __restrict__ eidx,
                const int* __restrict__ pos, const u16* __restrict__ wef,
                const float* __restrict__ b2v, const float* __restrict__ bc1v,
                const float* __restrict__ wc2v,
                u16* __restrict__ m_ij, float* __restrict__ x_acc, int ebase0) {
  extern __shared__ char smem[];
  const int tid = threadIdx.x;
  {
    const u32x4* src = reinterpret_cast<const u32x4*>(wef);
    u32x4* dst = reinterpret_cast<u32x4*>(smem);
    for (int i2 = tid; i2 < 4608; i2 += 1024) dst[i2] = src[i2];  // 73728 B
  }
  const int w = tid >> 6, lane = tid & 63;
  const int g = lane >> 4, c15 = lane & 15;
  const int e4 = lane >> 2, q4 = lane & 3;
  const u16* w1tf = (const u16*)smem;             //  8192 B
  const u16* w2f  = (const u16*)(smem + 8192);    // 32768 B
  const u16* wc1f = (const u16*)(smem + 40960);   // 32768 B
  u16* atail = (u16*)(smem + 73728 + w * 1024);   // [16][32] u16, zero-persistent
  u16* mbuf  = (u16*)(smem + 90112 + w * 4352);   // [16][136] u16
  *reinterpret_cast<u32x4*>((char*)atail + lane * 16) = (u32x4){0, 0, 0, 0};
  __syncthreads();

  float b2r[8], bc1r[8], wc2r[8];
#pragma unroll
  for (int t = 0; t < 8; ++t) {
    b2r[t]  = b2v[t * 16 + c15];
    bc1r[t] = bc1v[t * 16 + c15];
    wc2r[t] = wc2v[t * 16 + c15];
  }

  // ---- prologue: load tile bt0 fully into registers ----
  int bt = blockIdx.x;
  int r_v = 0, c_v = 0, p_v = 0;
  float xr0 = 0.f, xr1 = 0.f, xr2 = 0.f, xq0 = 0.f, xq1 = 0.f, xq2 = 0.f;
  f32x4 eav;
  short8 ga[4], gb[4];
  {
    int wt = bt * 16 + w;                        // <= 255*16+15 < 25000, always valid
    int eb = ebase0 + wt * 16;
    if (lane < 16) {
      int gi = eb + lane;
      r_v = eidx[gi]; c_v = eidx[E_CNT + gi]; p_v = pos[gi];
      xr0 = xc[3 * r_v + 0]; xr1 = xc[3 * r_v + 1]; xr2 = xc[3 * r_v + 2];
      xq0 = xc[3 * c_v + 0]; xq1 = xc[3 * c_v + 1]; xq2 = xc[3 * c_v + 2];
    }
    eav = *reinterpret_cast<const f32x4*>(ea + (size_t)(eb + e4) * 16 + q4 * 4);
    int re = __shfl(r_v, c15, 64);
    int ce = __shfl(c_v, c15, 64);
    const u16* pa = hp + (size_t)re * 256 + g * 8;
    const u16* pb = hp + (size_t)ce * 256 + 128 + g * 8;
#pragma unroll
    for (int s = 0; s < 4; ++s) ga[s] = *reinterpret_cast<const short8*>(pa + s * 32);
#pragma unroll
    for (int s = 0; s < 4; ++s) gb[s] = *reinterpret_cast<const short8*>(pb + s * 32);
  }

  for (; bt < 1563; bt += gridDim.x) {
    int wt = bt * 16 + w;
    if (wt >= 25000) continue;                   // only final tile of one block; no successor
    // A: geometry from prefetched regs
    if (lane < 16) {
      float d0 = xr0 - xq0, d1 = xr1 - xq1, d2 = xr2 - xq2;
      float dsq = d0 * d0 + d1 * d1 + d2 * d2;
      f32x4 cd = {d0, d1, d2, dsq};
      *reinterpret_cast<f32x4*>(mbuf + lane * 136 + 128) = cd;
    }
    int pc = __shfl(p_v, c15, 64);
    // C: atail build from prefetched eav
    {
      u16* row = atail + e4 * 32;
#pragma unroll
      for (int jj = 0; jj < 4; ++jj)
        row[1 + q4 * 4 + jj] = f2bf(eav[jj]);
      if (q4 == 0) {
        float dq = reinterpret_cast<const float*>(mbuf + e4 * 136 + 128)[3];
        row[0] = f2bf(dq);
      }
    }
    // E0: issue next-tile independent loads (indices, pos, ea)
    int btn = bt + gridDim.x;
    int wtn = btn * 16 + w;
    int wtn2 = (btn < 1563 && wtn < 25000) ? wtn : 0;   // clamp: values unused if invalid
    int ebn = ebase0 + wtn2 * 16;
    int r_n = 0, c_n = 0, p_n = 0;
    if (lane < 16) {
      int gin = ebn + lane;
      r_n = eidx[gin]; c_n = eidx[E_CNT + gin]; p_n = pos[gin];
    }
    f32x4 eav_n = *reinterpret_cast<const f32x4*>(ea + (size_t)(ebn + e4) * 16 + q4 * 4);
    // D: tail MFMA (K=32), B from LDS
    short8 af8 = *reinterpret_cast<const short8*>(atail + c15 * 32 + g * 8);
    f32x4 acc[8];
#pragma unroll
    for (int t = 0; t < 8; ++t) acc[t] = (f32x4){0.f, 0.f, 0.f, 0.f};
#pragma unroll
    for (int t = 0; t < 8; ++t) {
      short8 bf = *reinterpret_cast<const short8*>(w1tf + (t * 64 + lane) * 8);
      acc[t] = __builtin_amdgcn_mfma_f32_16x16x32_bf16(af8, bf, acc[t], 0, 0, 0);
    }
    // F: tail C -> mbuf (raw), combine in-register -> layer-2 A frags (ga/gb last use)
#pragma unroll
    for (int t = 0; t < 8; ++t) {
      int col = t * 16 + c15;
#pragma unroll
      for (int i = 0; i < 4; ++i)
        mbuf[(g * 4 + i) * 136 + col] = f2bf(acc[t][i]);
    }
    short8 a2[4];
#pragma unroll
    for (int s = 0; s < 4; ++s) {
      short8 tl = *reinterpret_cast<const short8*>(mbuf + c15 * 136 + s * 32 + g * 8);
      short8 o;
#pragma unroll
      for (int j = 0; j < 8; ++j) {
        float v = bf2f((u16)tl[j]) + bf2f((u16)ga[s][j]) + bf2f((u16)gb[s][j]);
        o[j] = (short)f2bf(siluf(v));
      }
      a2[s] = o;
    }
    // G: layer 2 MFMA (B from LDS)
    f32x4 acc2[8];
#pragma unroll
    for (int t = 0; t < 8; ++t) acc2[t] = (f32x4){0.f, 0.f, 0.f, 0.f};
#pragma unroll
    for (int s = 0; s < 4; ++s) {
#pragma unroll
      for (int t = 0; t < 8; ++t) {
        short8 bf = *reinterpret_cast<const short8*>(w2f + ((t * 4 + s) * 64 + lane) * 8);
        acc2[t] = __builtin_amdgcn_mfma_f32_16x16x32_bf16(a2[s], bf, acc2[t], 0, 0, 0);
      }
    }
    // E1: dependent next-tile loads (x coords, hp gathers) — eidx_n has arrived by now
    float xr0n = 0.f, xr1n = 0.f, xr2n = 0.f, xq0n = 0.f, xq1n = 0.f, xq2n = 0.f;
    if (lane < 16) {
      xr0n = xc[3 * r_n + 0]; xr1n = xc[3 * r_n + 1]; xr2n = xc[3 * r_n + 2];
      xq0n = xc[3 * c_n + 0]; xq1n = xc[3 * c_n + 1]; xq2n = xc[3 * c_n + 2];
    }
    int ren = __shfl(r_n, c15, 64);
    int cen = __shfl(c_n, c15, 64);
    short8 ga_n[4], gb_n[4];
    {
      const u16* pa = hp + (size_t)ren * 256 + g * 8;
      const u16* pb = hp + (size_t)cen * 256 + 128 + g * 8;
#pragma unroll
      for (int s = 0; s < 4; ++s) ga_n[s] = *reinterpret_cast<const short8*>(pa + s * 32);
#pragma unroll
      for (int s = 0; s < 4; ++s) gb_n[s] = *reinterpret_cast<const short8*>(pb + s * 32);
    }
    // H: m2 C -> mbuf, a3 + m_ij store
#pragma unroll
    for (int t = 0; t < 8; ++t) {
      int col = t * 16 + c15;
#pragma unroll
      for (int i = 0; i < 4; ++i)
        mbuf[(g * 4 + i) * 136 + col] = f2bf(siluf(acc2[t][i] + b2r[t]));
    }
    short8 a3[4];
#pragma unroll
    for (int s = 0; s < 4; ++s) {
      a3[s] = *reinterpret_cast<const short8*>(mbuf + c15 * 136 + s * 32 + g * 8);
      *reinterpret_cast<short8*>(m_ij + (size_t)pc * 128 + s * 32 + g * 8) = a3[s];
    }
    // I: coord MFMA (B from LDS)
    f32x4 acc3[8];
#pragma unroll
    for (int t = 0; t < 8; ++t) acc3[t] = (f32x4){0.f, 0.f, 0.f, 0.f};
#pragma unroll
    for (int s = 0; s < 4; ++s) {
#pragma unroll
      for (int t = 0; t < 8; ++t) {
        short8 bf = *reinterpret_cast<const short8*>(wc1f + ((t * 4 + s) * 64 + lane) * 8);
        acc3[t] = __builtin_amdgcn_mfma_f32_16x16x32_bf16(a3[s], bf, acc3[t], 0, 0, 0);
      }
    }
    // J: coord weight dot + reduce + atomics (uses CURRENT r_v / cd)
    float p4[4] = {0.f, 0.f, 0.f, 0.f};
#pragma unroll
    for (int t = 0; t < 8; ++t)
#pragma unroll
      for (int i = 0; i < 4; ++i)
        p4[i] += siluf(acc3[t][i] + bc1r[t]) * wc2r[t];
#pragma unroll
    for (int m = 1; m <= 8; m <<= 1) {
#pragma unroll
      for (int i = 0; i < 4; ++i) p4[i] += __shfl_xor(p4[i], m, 64);
    }
    int rr[4];
#pragma unroll
    for (int i = 0; i < 4; ++i) rr[i] = __shfl(r_v, g * 4 + i, 64);
    if (c15 == 0) {
#pragma unroll
      for (int i = 0; i < 4; ++i) {
        f32x4 cd = *reinterpret_cast<const f32x4*>(mbuf + (g * 4 + i) * 136 + 128);
        float fac = rsqrtf(cd[3] + 1e-8f) * tanhf(p4[i]);
        atomicAdd(&x_acc[rr[i] * 4 + 0], cd[0] * fac);
        atomicAdd(&x_acc[rr[i] * 4 + 1], cd[1] * fac);
        atomicAdd(&x_acc[rr[i] * 4 + 2], cd[2] * fac);
      }
    }
    // K: rotate prefetched registers into current
    r_v = r_n; c_v = c_n; p_v = p_n;
    xr0 = xr0n; xr1 = xr1n; xr2 = xr2n;
    xq0 = xq0n; xq1 = xq1n; xq2 = xq2n;
    eav = eav_n;
#pragma unroll
    for (int s = 0; s < 4; ++s) { ga[s] = ga_n[s]; gb[s] = gb_n[s]; }
  }
}

// ---------------- gather: m_i[n] = sum of contiguous m_ij slot rows ----------------
template <int ACC>
__global__ __launch_bounds__(256)
void k_gather(const u16* __restrict__ m_ij, const int* __restrict__ rp,
              float* __restrict__ m_i) {
  const int tid = threadIdx.x, w = tid >> 6, lane = tid & 63;
  const int grp = lane >> 4, c16 = lane & 15;
  int node = blockIdx.x * 4 + w;                 // 12500*4 == 50000
  int beg = rp[node], end = rp[node + 1];
  float a[8] = {0.f, 0.f, 0.f, 0.f, 0.f, 0.f, 0.f, 0.f};
  for (int j = beg + grp; j < end; j += 4) {
    short8 v = *reinterpret_cast<const short8*>(m_ij + (size_t)j * 128 + c16 * 8);
#pragma unroll
    for (int k = 0; k < 8; ++k) a[k] += bf2f((u16)v[k]);
  }
#pragma unroll
  for (int k = 0; k < 8; ++k) {
    a[k] += __shfl_xor(a[k], 16, 64);
    a[k] += __shfl_xor(a[k], 32, 64);
  }
  if (grp == 0) {
    float* dst = m_i + node * 128 + c16 * 8;
    if (ACC) {
      f32x4 o0 = *reinterpret_cast<const f32x4*>(dst);
      f32x4 o1 = *reinterpret_cast<const f32x4*>(dst + 4);
#pragma unroll
      for (int k = 0; k < 4; ++k) { o0[k] += a[k]; o1[k] += a[4 + k]; }
      *reinterpret_cast<f32x4*>(dst) = o0;
      *reinterpret_cast<f32x4*>(dst + 4) = o1;
    } else {
      f32x4 o0 = {a[0], a[1], a[2], a[3]};
      f32x4 o1 = {a[4], a[5], a[6], a[7]};
      *reinterpret_cast<f32x4*>(dst) = o0;
      *reinterpret_cast<f32x4*>(dst + 4) = o1;
    }
  }
}

// ---------------- node kernel ----------------
__global__ __launch_bounds__(256)
void egnn_node2(const float* __restrict__ h, const float* __restrict__ m_i,
                const u16* __restrict__ wnf,
                const float* __restrict__ bn1, const float* __restrict__ bn2,
                const float* __restrict__ lng, const float* __restrict__ lnb,
                float* __restrict__ h_out) {
  __shared__ u16 mbuf_all[4][2176];
  const int tid = threadIdx.x, w = tid >> 6, lane = tid & 63;
  const int g = lane >> 4, c15 = lane & 15;
  u16* mbuf = mbuf_all[w];
  const u16* wn1f = wnf;
  const u16* wn2f = wnf + 32768;

  float bn1r[8], bn2r[8], lngr[8], lnbr[8];
#pragma unroll
  for (int t = 0; t < 8; ++t) {
    bn1r[t] = bn1[t * 16 + c15];
    bn2r[t] = bn2[t * 16 + c15];
    lngr[t] = lng[t * 16 + c15];
    lnbr[t] = lnb[t * 16 + c15];
  }

  int wt = blockIdx.x * 4 + w;                   // 782*4 = 3128 >= 3125
  if (wt >= 3125) return;
  int nbase = wt * 16;
  int nr = nbase + c15;
  short8 af[8];
#pragma unroll
  for (int s = 0; s < 4; ++s) {
    const float* p = h + nr * 128 + s * 32 + g * 8;
    af[s] = pack8(*reinterpret_cast<const f32x4*>(p),
                  *reinterpret_cast<const f32x4*>(p + 4));
  }
#pragma unroll
  for (int s = 0; s < 4; ++s) {
    const float* p = m_i + nr * 128 + s * 32 + g * 8;
    af[4 + s] = pack8(*reinterpret_cast<const f32x4*>(p),
                      *reinterpret_cast<const f32x4*>(p + 4));
  }
  f32x4 acc[8];
#pragma unroll
  for (int t = 0; t < 8; ++t) acc[t] = (f32x4){0.f, 0.f, 0.f, 0.f};
#pragma unroll
  for (int s = 0; s < 8; ++s) {
#pragma unroll
    for (int t = 0; t < 8; ++t) {
      short8 bf = *reinterpret_cast<const short8*>(wn1f + ((t * 8 + s) * 64 + lane) * 8);
      acc[t] = __builtin_amdgcn_mfma_f32_16x16x32_bf16(af[s], bf, acc[t], 0, 0, 0);
    }
  }
#pragma unroll
  for (int t = 0; t < 8; ++t) {
    int col = t * 16 + c15;
#pragma unroll
    for (int i = 0; i < 4; ++i)
      mbuf[(g * 4 + i) * 136 + col] = f2bf(siluf(acc[t][i] + bn1r[t]));
  }
  short8 a2[4];
#pragma unroll
  for (int s = 0; s < 4; ++s)
    a2[s] = *reinterpret_cast<const short8*>(mbuf + c15 * 136 + s * 32 + g * 8);
  f32x4 acc2[8];
#pragma unroll
  for (int t = 0; t < 8; ++t) acc2[t] = (f32x4){0.f, 0.f, 0.f, 0.f};
#pragma unroll
  for (int s = 0; s < 4; ++s) {
#pragma unroll
    for (int t = 0; t < 8; ++t) {
      short8 bf = *reinterpret_cast<const short8*>(wn2f + ((t * 4 + s) * 64 + lane) * 8);
      acc2[t] = __builtin_amdgcn_mfma_f32_16x16x32_bf16(a2[s], bf, acc2[t], 0, 0, 0);
    }
  }
  float vres[8][4];
  float s1[4] = {0.f, 0.f, 0.f, 0.f}, s2[4] = {0.f, 0.f, 0.f, 0.f};
#pragma unroll
  for (int t = 0; t < 8; ++t)
#pragma unroll
    for (int i = 0; i < 4; ++i) {
      int n = nbase + g * 4 + i;
      float v = acc2[t][i] + bn2r[t] + h[n * 128 + t * 16 + c15];
      vres[t][i] = v; s1[i] += v; s2[i] += v * v;
    }
#pragma unroll
  for (int m = 1; m <= 8; m <<= 1) {
#pragma unroll
    for (int i = 0; i < 4; ++i) {
      s1[i] += __shfl_xor(s1[i], m, 64);
      s2[i] += __shfl_xor(s2[i], m, 64);
    }
  }
  float mu[4], rstd[4];
#pragma unroll
  for (int i = 0; i < 4; ++i) {
    mu[i] = s1[i] * (1.0f / 128.0f);
    float var = s2[i] * (1.0f / 128.0f) - mu[i] * mu[i];
    rstd[i] = rsqrtf(var + 1e-5f);
  }
#pragma unroll
  for (int t = 0; t < 8; ++t)
#pragma unroll
    for (int i = 0; i < 4; ++i) {
      int n = nbase + g * 4 + i;
      h_out[n * 128 + t * 16 + c15] =
          (vres[t][i] - mu[i]) * rstd[i] * lngr[t] + lnbr[t];
    }
}

// ---------------- x_out ----------------
__global__ void egnn_xout(const float* __restrict__ x, const float* __restrict__ x_acc,
                          const int* __restrict__ degs, float* __restrict__ xo) {
  int n = blockIdx.x * 256 + threadIdx.x;
  if (n < N_CNT) {
    float dg = fmaxf((float)(degs[n] + degs[N_CNT + n]), 1.0f);
    xo[n * 3 + 0] = x[n * 3 + 0] + x_acc[n * 4 + 0] / dg;
    xo[n * 3 + 1] = x[n * 3 + 1] + x_acc[n * 4 + 1] / dg;
    xo[n * 3 + 2] = x[n * 3 + 2] + x_acc[n * 4 + 2] / dg;
  }
}

extern "C" void kernel_launch(void* const* d_in, const int* in_sizes, int n_in,
                              void* d_out, int out_size, void* d_ws, size_t ws_size,
                              hipStream_t stream) {
  const float* h     = (const float*)d_in[0];
  const float* x     = (const float*)d_in[1];
  const float* ea    = (const float*)d_in[2];
  const float* we_w1 = (const float*)d_in[3];
  const float* we_b1 = (const float*)d_in[4];
  const float* we_w2 = (const float*)d_in[5];
  const float* we_b2 = (const float*)d_in[6];
  const float* wc_w1 = (const float*)d_in[7];
  const float* wc_b1 = (const float*)d_in[8];
  const float* wc_w2 = (const float*)d_in[9];
  const float* wn_w1 = (const float*)d_in[10];
  const float* wn_b1 = (const float*)d_in[11];
  const float* wn_w2 = (const float*)d_in[12];
  const float* wn_b2 = (const float*)d_in[13];
  const float* ln_g  = (const float*)d_in[14];
  const float* ln_b  = (const float*)d_in[15];
  const int* eidx    = (const int*)d_in[16];
  float* out = (float*)d_out;
  char* ws = (char*)d_ws;

  u16* wef    = (u16*)(ws);                      //     73,728
  u16* w1abf  = (u16*)(ws + 73728);              //     65,536
  u16* wnf    = (u16*)(ws + 139264);             //     98,304
  u16* hp     = (u16*)(ws + 237568);             // 25,600,000
  float* m_i  = (float*)(ws + 25837568);         // 25,600,000
  float* xacc = (float*)(ws + 51437568);         //    800,000
  int* degs   = (int*)(ws + 52237568);           //    400,000
  int* curs   = (int*)(ws + 52637568);           //    400,000
  int* rps    = (int*)(ws + 53037568);           //    400,016
  int* pos    = (int*)(ws + 53437584);           //  3,200,000
  int* bsum   = (int*)(ws + 56637584);           //        800
  int* boff   = (int*)(ws + 56638384);           //        816
  u16* m_ij   = (u16*)(ws + 56639200);           // 102,400,000 (end 159,039,200)

  k_wf<<<464, 256, 0, stream>>>(we_w1, we_w2, wc_w1, wn_w1, wn_w2, wef, w1abf, wnf);

  hipFuncSetAttribute(reinterpret_cast<const void*>(k_hp),
                      hipFuncAttributeMaxDynamicSharedMemorySize, 65536);
  k_hp<<<782, 256, 65536, stream>>>(h, w1abf, we_b1, hp);

  hipMemsetAsync(ws + 51437568, 0, 1600000, stream);   // xacc + degs + curs
  k_deg<<<3125, 256, 0, stream>>>(eidx, degs);
  k_bsum<<<196, 256, 0, stream>>>(degs, bsum);
  k_mid<<<1, 128, 0, stream>>>(bsum, boff, rps);
  k_rp<<<196, 256, 0, stream>>>(degs, boff, rps);
  k_scatter<<<3125, 256, 0, stream>>>(eidx, rps, curs, pos);

  hipFuncSetAttribute(reinterpret_cast<const void*>(egnn_edge6),
                      hipFuncAttributeMaxDynamicSharedMemorySize, 159744);
  egnn_edge6<<<256, 1024, 159744, stream>>>(hp, x, ea, eidx, pos, wef,
                                            we_b2, wc_b1, wc_w2, m_ij, xacc, 0);
  k_gather<0><<<12500, 256, 0, stream>>>(m_ij, rps, m_i);
  egnn_edge6<<<256, 1024, 159744, stream>>>(hp, x, ea, eidx, pos, wef,
                                            we_b2, wc_b1, wc_w2, m_ij, xacc, EB_CNT);
  k_gather<1><<<12500, 256, 0, stream>>>(m_ij, rps + (N_CNT + 1), m_i);

  egnn_node2<<<782, 256, 0, stream>>>(h, m_i, wnf, wn_b1, wn_b2, ln_g, ln_b, out);
  egnn_xout<<<196, 256, 0, stream>>>(x, xacc, degs, out + 6400000);
}

// Round 10
// 445.103 us; speedup vs baseline: 1.0649x; 1.0649x over previous
//
#include <hip/hip_runtime.h>

typedef unsigned short u16;
typedef unsigned int u32;
using short8 = __attribute__((ext_vector_type(8))) short;
using f32x4  = __attribute__((ext_vector_type(4))) float;
using u32x4  = __attribute__((ext_vector_type(4))) u32;

#define N_CNT 50000
#define E_CNT 800000
#define EB_CNT 400000   // edges per batch (2 batches)

// RTNE float->bf16 via native __bf16 (lowers to v_cvt_pk_bf16_f32 on gfx950;
// replaces the 4-op manual bit-trick -- the single change vs the 455us round-6 kernel)
__device__ __forceinline__ u16 f2bf(float f) {
  __bf16 b = (__bf16)f;
  return __builtin_bit_cast(u16, b);
}
__device__ __forceinline__ float bf2f(u16 v) {
  u32 u = ((u32)v) << 16;
  return __builtin_bit_cast(float, u);
}
__device__ __forceinline__ short8 pack8(f32x4 v0, f32x4 v1) {
  short8 r;
#pragma unroll
  for (int j = 0; j < 4; ++j) r[j] = (short)f2bf(v0[j]);
#pragma unroll
  for (int j = 0; j < 4; ++j) r[4 + j] = (short)f2bf(v1[j]);
  return r;
}
__device__ __forceinline__ float siluf(float v) {
  return __fdividef(v, 1.f + __expf(-v));
}

// ---------------- prep: weight fragments (MFMA B layout) ----------------
// frag element (tile t, kstep s, lane l, i): B[k=32s+8*(l>>4)+i][n=16t+(l&15)]
// wef:   w1tail [0,4096) | w2f [4096,20480) | wc1f [20480,36864)   (u16 idx)
// w1abf: 32768 u16   (K=128 -> N=256: [W1a | W1b], 16t x 4s)
// wnf:   wn1f 32768 | wn2f 16384
__global__ void k_wf(const float* __restrict__ w1, const float* __restrict__ w2,
                     const float* __restrict__ wc1, const float* __restrict__ wn1,
                     const float* __restrict__ wn2,
                     u16* __restrict__ wef, u16* __restrict__ w1abf,
                     u16* __restrict__ wnf) {
  int idx = blockIdx.x * 256 + threadIdx.x;     // 464*256 == 118784 exact
  int i = idx & 7, l = (idx >> 3) & 63;
  int kb = 8 * (l >> 4) + i;
  int n16 = l & 15;
  if (idx < 4096) {                             // w1tail: 8t x 1s, k = 256..287 of W1
    int t = idx >> 9;
    int k = kb, n = 16 * t + n16;
    wef[idx] = (k < 17) ? f2bf(w1[(256 + k) * 128 + n]) : (u16)0;
  } else if (idx < 20480) {                     // w2f: 8t x 4s
    int u = idx - 4096, rest = u >> 9;
    int s = rest & 3, t = rest >> 2;
    wef[idx] = f2bf(w2[(32 * s + kb) * 128 + 16 * t + n16]);
  } else if (idx < 36864) {                     // wc1f: 8t x 4s
    int u = idx - 20480, rest = u >> 9;
    int s = rest & 3, t = rest >> 2;
    wef[idx] = f2bf(wc1[(32 * s + kb) * 128 + 16 * t + n16]);
  } else if (idx < 69632) {                     // w1abf: 16t x 4s, K=128, N=256
    int u = idx - 36864, rest = u >> 9;
    int s = rest & 3, t = rest >> 2;
    int k = 32 * s + kb, n = 16 * t + n16;
    float v = (n < 128) ? w1[k * 128 + n] : w1[(128 + k) * 128 + (n - 128)];
    w1abf[u] = f2bf(v);
  } else if (idx < 102400) {                    // wn1f: 8t x 8s (K=256)
    int u = idx - 69632, rest = u >> 9;
    int s = rest & 7, t = rest >> 3;
    wnf[u] = f2bf(wn1[(32 * s + kb) * 128 + 16 * t + n16]);
  } else if (idx < 118784) {                    // wn2f: 8t x 4s
    int u = idx - 102400, rest = u >> 9;
    int s = rest & 3, t = rest >> 2;
    wnf[32768 + u] = f2bf(wn2[(32 * s + kb) * 128 + 16 * t + n16]);
  }
}

// ---------------- hp = h @ [W1a|W1b] + [b1|0]  (bf16 [N][256]) ----------------
__global__ __launch_bounds__(256)
void k_hp(const float* __restrict__ h, const u16* __restrict__ w1abf,
          const float* __restrict__ b1v, u16* __restrict__ hp) {
  extern __shared__ char smem[];
  u16* wl = (u16*)smem;
  const int tid = threadIdx.x;
  {
    const u32x4* src = reinterpret_cast<const u32x4*>(w1abf);
    u32x4* dst = reinterpret_cast<u32x4*>(smem);
    for (int i2 = tid; i2 < 4096; i2 += 256) dst[i2] = src[i2];
  }
  __syncthreads();
  const int w = tid >> 6, lane = tid & 63;
  const int g = lane >> 4, c15 = lane & 15;
  float b1r[8];
#pragma unroll
  for (int t = 0; t < 8; ++t) b1r[t] = b1v[t * 16 + c15];

  int wt = blockIdx.x * 4 + w;                   // 782*4 = 3128 >= 3125
  if (wt >= 3125) return;
  int nbase = wt * 16;
  int nr = nbase + c15;
  short8 af[4];
#pragma unroll
  for (int s = 0; s < 4; ++s) {
    const float* p = h + nr * 128 + s * 32 + g * 8;
    af[s] = pack8(*reinterpret_cast<const f32x4*>(p),
                  *reinterpret_cast<const f32x4*>(p + 4));
  }
  f32x4 acc[16];
#pragma unroll
  for (int t = 0; t < 16; ++t) acc[t] = (f32x4){0.f, 0.f, 0.f, 0.f};
#pragma unroll
  for (int s = 0; s < 4; ++s) {
#pragma unroll
    for (int t = 0; t < 16; ++t) {
      short8 bf = *reinterpret_cast<const short8*>(wl + ((t * 4 + s) * 64 + lane) * 8);
      acc[t] = __builtin_amdgcn_mfma_f32_16x16x32_bf16(af[s], bf, acc[t], 0, 0, 0);
    }
  }
#pragma unroll
  for (int t = 0; t < 16; ++t) {
    float bb = (t < 8) ? b1r[t] : 0.f;
    int col = t * 16 + c15;
#pragma unroll
    for (int i = 0; i < 4; ++i)
      hp[(size_t)(nbase + g * 4 + i) * 256 + col] = f2bf(acc[t][i] + bb);
  }
}

// ---------------- CSR build (per-batch) ----------------
__global__ void k_deg(const int* __restrict__ eidx, int* __restrict__ degs) {
  int e = blockIdx.x * 256 + threadIdx.x;       // 3125*256 == 800000
  int b = (e >= EB_CNT) ? 1 : 0;
  atomicAdd(&degs[b * N_CNT + eidx[e]], 1);
}

__global__ void k_bsum(const int* __restrict__ degs, int* __restrict__ bsum) {
  int bid = blockIdx.x;                          // 196 = 2 batches x 98 chunks
  int batch = bid / 98, chunk = bid % 98;
  const int* deg = degs + batch * N_CNT;
  int b0 = chunk * 512 + threadIdx.x;
  int b1 = b0 + 256;
  int v = ((b0 < N_CNT) ? deg[b0] : 0) + ((b1 < N_CNT) ? deg[b1] : 0);
#pragma unroll
  for (int m = 1; m <= 32; m <<= 1) v += __shfl_xor(v, m, 64);
  __shared__ int ws[4];
  if ((threadIdx.x & 63) == 0) ws[threadIdx.x >> 6] = v;
  __syncthreads();
  if (threadIdx.x == 0) bsum[bid] = ws[0] + ws[1] + ws[2] + ws[3];
}

__global__ void k_mid(const int* __restrict__ bsum, int* __restrict__ boff,
                      int* __restrict__ rps) {
  int wv = threadIdx.x >> 6, lane = threadIdx.x & 63;
  if (wv >= 2) return;
  const int* bs = bsum + wv * 98;
  int* bo = boff + wv * 98;
  int carry = 0;
  for (int base = 0; base < 98; base += 64) {
    int idx = base + lane;
    int v = (idx < 98) ? bs[idx] : 0;
    int inc = v;
#pragma unroll
    for (int d = 1; d <= 32; d <<= 1) {
      int u = __shfl_up(inc, d, 64);
      if (lane >= d) inc += u;
    }
    if (idx < 98) bo[idx] = carry + inc - v;
    carry += __shfl(inc, 63, 64);
  }
  if (lane == 0) rps[wv * (N_CNT + 1) + N_CNT] = EB_CNT;
}

__global__ void k_rp(const int* __restrict__ degs, const int* __restrict__ boff,
                     int* __restrict__ rps) {
  int bid = blockIdx.x;
  int batch = bid / 98, chunk = bid % 98;
  const int* deg = degs + batch * N_CNT;
  int* rp = rps + batch * (N_CNT + 1);
  int i0 = chunk * 512 + 2 * threadIdx.x, i1 = i0 + 1;
  int a = (i0 < N_CNT) ? deg[i0] : 0;
  int b = (i1 < N_CNT) ? deg[i1] : 0;
  int s = a + b, lane = threadIdx.x & 63, wv = threadIdx.x >> 6;
  int inc = s;
#pragma unroll
  for (int d = 1; d <= 32; d <<= 1) {
    int u = __shfl_up(inc, d, 64);
    if (lane >= d) inc += u;
  }
  __shared__ int ws2[4];
  if (lane == 63) ws2[wv] = inc;
  __syncthreads();
  int woff = 0;
  for (int k = 0; k < wv; ++k) woff += ws2[k];
  int excl = boff[bid] + woff + inc - s;
  if (i0 < N_CNT) rp[i0] = excl;
  if (i1 < N_CNT) rp[i1] = excl + a;
}

__global__ void k_scatter(const int* __restrict__ eidx, const int* __restrict__ rps,
                          int* __restrict__ curs, int* __restrict__ pos) {
  int e = blockIdx.x * 256 + threadIdx.x;
  int b = (e >= EB_CNT) ? 1 : 0;
  int r = eidx[e];
  int p = atomicAdd(&curs[b * N_CNT + r], 1);
  pos[e] = rps[b * (N_CNT + 1) + r] + p;
}

// ---------------- edge kernel ----------------
// 1024 thr = 16 waves, 16 edges/wave. ALL weight frags in LDS (round-6 proven).
// LDS: w1tf 8192 | w2f 32768 | wc1f 32768 | atail 16x1024 | mbuf 16x4352 = 159744.
__global__ __launch_bounds__(1024, 4)
void egnn_edge4(const u16* __restrict__ hp, const float* __restrict__ xc,
                const float* __restrict__ ea, const int* __restrict__ eidx,
                const int* __restrict__ pos, const u16* __restrict__ wef,
                const float* __restrict__ b2v, const float* __restrict__ bc1v,
                const float* __restrict__ wc2v,
                u16* __restrict__ m_ij, float* __restrict__ x_acc, int ebase0) {
  extern __shared__ char smem[];
  const int tid = threadIdx.x;
  {
    const u32x4* src = reinterpret_cast<const u32x4*>(wef);
    u32x4* dst = reinterpret_cast<u32x4*>(smem);
    for (int i2 = tid; i2 < 4608; i2 += 1024) dst[i2] = src[i2];  // 73728 B
  }
  const int w = tid >> 6, lane = tid & 63;
  const int g = lane >> 4, c15 = lane & 15;
  const int e4 = lane >> 2, q4 = lane & 3;
  const u16* w1tf = (const u16*)smem;             //  8192 B
  const u16* w2f  = (const u16*)(smem + 8192);    // 32768 B
  const u16* wc1f = (const u16*)(smem + 40960);   // 32768 B
  u16* atail = (u16*)(smem + 73728 + w * 1024);   // [16][32] u16, zero-persistent
  u16* mbuf  = (u16*)(smem + 90112 + w * 4352);   // [16][136] u16
  // zero atail once (cols 17..31 stay zero forever)
  *reinterpret_cast<u32x4*>((char*)atail + lane * 16) = (u32x4){0, 0, 0, 0};
  __syncthreads();

  float b2r[8], bc1r[8], wc2r[8];
#pragma unroll
  for (int t = 0; t < 8; ++t) {
    b2r[t]  = b2v[t * 16 + c15];
    bc1r[t] = bc1v[t * 16 + c15];
    wc2r[t] = wc2v[t * 16 + c15];
  }

  for (int bt = blockIdx.x; bt < 1563; bt += gridDim.x) {
    int wt = bt * 16 + w;
    if (wt >= 25000) continue;
    const int eb = ebase0 + wt * 16;
    // geometry (lanes 0..15)
    int r_v = 0, c_v = 0, p_v = 0;
    if (lane < 16) {
      int gi = eb + lane;
      r_v = eidx[gi]; c_v = eidx[E_CNT + gi]; p_v = pos[gi];
      float d0 = xc[3 * r_v + 0] - xc[3 * c_v + 0];
      float d1 = xc[3 * r_v + 1] - xc[3 * c_v + 1];
      float d2 = xc[3 * r_v + 2] - xc[3 * c_v + 2];
      float dsq = d0 * d0 + d1 * d1 + d2 * d2;
      f32x4 cd = {d0, d1, d2, dsq};
      *reinterpret_cast<f32x4*>(mbuf + lane * 136 + 128) = cd;
    }
    int re = __shfl(r_v, c15, 64);
    int ce = __shfl(c_v, c15, 64);
    int pc = __shfl(p_v, c15, 64);
    // hp gathers in A-fragment pattern (row = c15's edge, cols 32s+8g+j)
    short8 ga[4], gb[4];
    {
      const u16* pa = hp + (size_t)re * 256 + g * 8;
      const u16* pb = hp + (size_t)ce * 256 + 128 + g * 8;
#pragma unroll
      for (int s = 0; s < 4; ++s) ga[s] = *reinterpret_cast<const short8*>(pa + s * 32);
#pragma unroll
      for (int s = 0; s < 4; ++s) gb[s] = *reinterpret_cast<const short8*>(pb + s * 32);
    }
    // tail A-tile: [dsq, ea0..15, 0(persistent)..]
    {
      u16* row = atail + e4 * 32;
      f32x4 eav = *reinterpret_cast<const f32x4*>(ea + (size_t)(eb + e4) * 16 + q4 * 4);
#pragma unroll
      for (int jj = 0; jj < 4; ++jj)
        row[1 + q4 * 4 + jj] = f2bf(eav[jj]);
      if (q4 == 0) {
        float dq = reinterpret_cast<const float*>(mbuf + e4 * 136 + 128)[3];
        row[0] = f2bf(dq);
      }
    }
    // tail MFMA (K=32), B from LDS
    short8 af8 = *reinterpret_cast<const short8*>(atail + c15 * 32 + g * 8);
    f32x4 acc[8];
#pragma unroll
    for (int t = 0; t < 8; ++t) acc[t] = (f32x4){0.f, 0.f, 0.f, 0.f};
#pragma unroll
    for (int t = 0; t < 8; ++t) {
      short8 bf = *reinterpret_cast<const short8*>(w1tf + (t * 64 + lane) * 8);
      acc[t] = __builtin_amdgcn_mfma_f32_16x16x32_bf16(af8, bf, acc[t], 0, 0, 0);
    }
    // tail C -> mbuf (raw, no bias/silu)
#pragma unroll
    for (int t = 0; t < 8; ++t) {
      int col = t * 16 + c15;
#pragma unroll
      for (int i = 0; i < 4; ++i)
        mbuf[(g * 4 + i) * 136 + col] = f2bf(acc[t][i]);
    }
    // combine in-register -> layer-2 A fragments (no m1 LDS round-trip)
    short8 a2[4];
#pragma unroll
    for (int s = 0; s < 4; ++s) {
      short8 tl = *reinterpret_cast<const short8*>(mbuf + c15 * 136 + s * 32 + g * 8);
      short8 o;
#pragma unroll
      for (int j = 0; j < 8; ++j) {
        float v = bf2f((u16)tl[j]) + bf2f((u16)ga[s][j]) + bf2f((u16)gb[s][j]);
        o[j] = (short)f2bf(siluf(v));
      }
      a2[s] = o;
    }
    // layer 2: m1 @ we_w2 (B from LDS)
    f32x4 acc2[8];
#pragma unroll
    for (int t = 0; t < 8; ++t) acc2[t] = (f32x4){0.f, 0.f, 0.f, 0.f};
#pragma unroll
    for (int s = 0; s < 4; ++s) {
#pragma unroll
      for (int t = 0; t < 8; ++t) {
        short8 bf = *reinterpret_cast<const short8*>(w2f + ((t * 4 + s) * 64 + lane) * 8);
        acc2[t] = __builtin_amdgcn_mfma_f32_16x16x32_bf16(a2[s], bf, acc2[t], 0, 0, 0);
      }
    }
    // m2 C -> mbuf (C->A transpose for m_ij + coord input)
#pragma unroll
    for (int t = 0; t < 8; ++t) {
      int col = t * 16 + c15;
#pragma unroll
      for (int i = 0; i < 4; ++i)
        mbuf[(g * 4 + i) * 136 + col] = f2bf(siluf(acc2[t][i] + b2r[t]));
    }
    // a3 + stream to m_ij[slot]
    short8 a3[4];
#pragma unroll
    for (int s = 0; s < 4; ++s) {
      a3[s] = *reinterpret_cast<const short8*>(mbuf + c15 * 136 + s * 32 + g * 8);
      *reinterpret_cast<short8*>(m_ij + (size_t)pc * 128 + s * 32 + g * 8) = a3[s];
    }
    // coord MLP (B from LDS)
    f32x4 acc3[8];
#pragma unroll
    for (int t = 0; t < 8; ++t) acc3[t] = (f32x4){0.f, 0.f, 0.f, 0.f};
#pragma unroll
    for (int s = 0; s < 4; ++s) {
#pragma unroll
      for (int t = 0; t < 8; ++t) {
        short8 bf = *reinterpret_cast<const short8*>(wc1f + ((t * 4 + s) * 64 + lane) * 8);
        acc3[t] = __builtin_amdgcn_mfma_f32_16x16x32_bf16(a3[s], bf, acc3[t], 0, 0, 0);
      }
    }
    float p4[4] = {0.f, 0.f, 0.f, 0.f};
#pragma unroll
    for (int t = 0; t < 8; ++t)
#pragma unroll
      for (int i = 0; i < 4; ++i)
        p4[i] += siluf(acc3[t][i] + bc1r[t]) * wc2r[t];
#pragma unroll
    for (int m = 1; m <= 8; m <<= 1) {
#pragma unroll
      for (int i = 0; i < 4; ++i) p4[i] += __shfl_xor(p4[i], m, 64);
    }
    int rr[4];
#pragma unroll
    for (int i = 0; i < 4; ++i) rr[i] = __shfl(r_v, g * 4 + i, 64);
    if (c15 == 0) {
#pragma unroll
      for (int i = 0; i < 4; ++i) {
        f32x4 cd = *reinterpret_cast<const f32x4*>(mbuf + (g * 4 + i) * 136 + 128);
        float fac = rsqrtf(cd[3] + 1e-8f) * tanhf(p4[i]);
        atomicAdd(&x_acc[rr[i] * 4 + 0], cd[0] * fac);
        atomicAdd(&x_acc[rr[i] * 4 + 1], cd[1] * fac);
        atomicAdd(&x_acc[rr[i] * 4 + 2], cd[2] * fac);
      }
    }
  }
}

// ---------------- gather: m_i[n] = sum of contiguous m_ij slot rows ----------------
template <int ACC>
__global__ __launch_bounds__(256)
void k_gather(const u16* __restrict__ m_ij, const int* __restrict__ rp,
              float* __restrict__ m_i) {
  const int tid = threadIdx.x, w = tid >> 6, lane = tid & 63;
  const int grp = lane >> 4, c16 = lane & 15;
  int node = blockIdx.x * 4 + w;                 // 12500*4 == 50000
  int beg = rp[node], end = rp[node + 1];
  float a[8] = {0.f, 0.f, 0.f, 0.f, 0.f, 0.f, 0.f, 0.f};
  for (int j = beg + grp; j < end; j += 4) {
    short8 v = *reinterpret_cast<const short8*>(m_ij + (size_t)j * 128 + c16 * 8);
#pragma unroll
    for (int k = 0; k < 8; ++k) a[k] += bf2f((u16)v[k]);
  }
#pragma unroll
  for (int k = 0; k < 8; ++k) {
    a[k] += __shfl_xor(a[k], 16, 64);
    a[k] += __shfl_xor(a[k], 32, 64);
  }
  if (grp == 0) {
    float* dst = m_i + node * 128 + c16 * 8;
    if (ACC) {
      f32x4 o0 = *reinterpret_cast<const f32x4*>(dst);
      f32x4 o1 = *reinterpret_cast<const f32x4*>(dst + 4);
#pragma unroll
      for (int k = 0; k < 4; ++k) { o0[k] += a[k]; o1[k] += a[4 + k]; }
      *reinterpret_cast<f32x4*>(dst) = o0;
      *reinterpret_cast<f32x4*>(dst + 4) = o1;
    } else {
      f32x4 o0 = {a[0], a[1], a[2], a[3]};
      f32x4 o1 = {a[4], a[5], a[6], a[7]};
      *reinterpret_cast<f32x4*>(dst) = o0;
      *reinterpret_cast<f32x4*>(dst + 4) = o1;
    }
  }
}

// ---------------- node kernel ----------------
__global__ __launch_bounds__(256)
void egnn_node2(const float* __restrict__ h, const float* __restrict__ m_i,
                const u16* __restrict__ wnf,
                const float* __restrict__ bn1, const float* __restrict__ bn2,
                const float* __restrict__ lng, const float* __restrict__ lnb,
                float* __restrict__ h_out) {
  __shared__ u16 mbuf_all[4][2176];
  const int tid = threadIdx.x, w = tid >> 6, lane = tid & 63;
  const int g = lane >> 4, c15 = lane & 15;
  u16* mbuf = mbuf_all[w];
  const u16* wn1f = wnf;
  const u16* wn2f = wnf + 32768;

  float bn1r[8], bn2r[8], lngr[8], lnbr[8];
#pragma unroll
  for (int t = 0; t < 8; ++t) {
    bn1r[t] = bn1[t * 16 + c15];
    bn2r[t] = bn2[t * 16 + c15];
    lngr[t] = lng[t * 16 + c15];
    lnbr[t] = lnb[t * 16 + c15];
  }

  int wt = blockIdx.x * 4 + w;                   // 782*4 = 3128 >= 3125
  if (wt >= 3125) return;
  int nbase = wt * 16;
  int nr = nbase + c15;
  short8 af[8];
#pragma unroll
  for (int s = 0; s < 4; ++s) {
    const float* p = h + nr * 128 + s * 32 + g * 8;
    af[s] = pack8(*reinterpret_cast<const f32x4*>(p),
                  *reinterpret_cast<const f32x4*>(p + 4));
  }
#pragma unroll
  for (int s = 0; s < 4; ++s) {
    const float* p = m_i + nr * 128 + s * 32 + g * 8;
    af[4 + s] = pack8(*reinterpret_cast<const f32x4*>(p),
                      *reinterpret_cast<const f32x4*>(p + 4));
  }
  f32x4 acc[8];
#pragma unroll
  for (int t = 0; t < 8; ++t) acc[t] = (f32x4){0.f, 0.f, 0.f, 0.f};
#pragma unroll
  for (int s = 0; s < 8; ++s) {
#pragma unroll
    for (int t = 0; t < 8; ++t) {
      short8 bf = *reinterpret_cast<const short8*>(wn1f + ((t * 8 + s) * 64 + lane) * 8);
      acc[t] = __builtin_amdgcn_mfma_f32_16x16x32_bf16(af[s], bf, acc[t], 0, 0, 0);
    }
  }
#pragma unroll
  for (int t = 0; t < 8; ++t) {
    int col = t * 16 + c15;
#pragma unroll
    for (int i = 0; i < 4; ++i)
      mbuf[(g * 4 + i) * 136 + col] = f2bf(siluf(acc[t][i] + bn1r[t]));
  }
  short8 a2[4];
#pragma unroll
  for (int s = 0; s < 4; ++s)
    a2[s] = *reinterpret_cast<const short8*>(mbuf + c15 * 136 + s * 32 + g * 8);
  f32x4 acc2[8];
#pragma unroll
  for (int t = 0; t < 8; ++t) acc2[t] = (f32x4){0.f, 0.f, 0.f, 0.f};
#pragma unroll
  for (int s = 0; s < 4; ++s) {
#pragma unroll
    for (int t = 0; t < 8; ++t) {
      short8 bf = *reinterpret_cast<const short8*>(wn2f + ((t * 4 + s) * 64 + lane) * 8);
      acc2[t] = __builtin_amdgcn_mfma_f32_16x16x32_bf16(a2[s], bf, acc2[t], 0, 0, 0);
    }
  }
  float vres[8][4];
  float s1[4] = {0.f, 0.f, 0.f, 0.f}, s2[4] = {0.f, 0.f, 0.f, 0.f};
#pragma unroll
  for (int t = 0; t < 8; ++t)
#pragma unroll
    for (int i = 0; i < 4; ++i) {
      int n = nbase + g * 4 + i;
      float v = acc2[t][i] + bn2r[t] + h[n * 128 + t * 16 + c15];
      vres[t][i] = v; s1[i] += v; s2[i] += v * v;
    }
#pragma unroll
  for (int m = 1; m <= 8; m <<= 1) {
#pragma unroll
    for (int i = 0; i < 4; ++i) {
      s1[i] += __shfl_xor(s1[i], m, 64);
      s2[i] += __shfl_xor(s2[i], m, 64);
    }
  }
  float mu[4], rstd[4];
#pragma unroll
  for (int i = 0; i < 4; ++i) {
    mu[i] = s1[i] * (1.0f / 128.0f);
    float var = s2[i] * (1.0f / 128.0f) - mu[i] * mu[i];
    rstd[i] = rsqrtf(var + 1e-5f);
  }
#pragma unroll
  for (int t = 0; t < 8; ++t)
#pragma unroll
    for (int i = 0; i < 4; ++i) {
      int n = nbase + g * 4 + i;
      h_out[n * 128 + t * 16 + c15] =
          (vres[t][i] - mu[i]) * rstd[i] * lngr[t] + lnbr[t];
    }
}

// ---------------- x_out ----------------
__global__ void egnn_xout(const float* __restrict__ x, const float* __restrict__ x_acc,
                          const int* __restrict__ degs, float* __restrict__ xo) {
  int n = blockIdx.x * 256 + threadIdx.x;
  if (n < N_CNT) {
    float dg = fmaxf((float)(degs[n] + degs[N_CNT + n]), 1.0f);
    xo[n * 3 + 0] = x[n * 3 + 0] + x_acc[n * 4 + 0] / dg;
    xo[n * 3 + 1] = x[n * 3 + 1] + x_acc[n * 4 + 1] / dg;
    xo[n * 3 + 2] = x[n * 3 + 2] + x_acc[n * 4 + 2] / dg;
  }
}

extern "C" void kernel_launch(void* const* d_in, const int* in_sizes, int n_in,
                              void* d_out, int out_size, void* d_ws, size_t ws_size,
                              hipStream_t stream) {
  const float* h     = (const float*)d_in[0];
  const float* x     = (const float*)d_in[1];
  const float* ea    = (const float*)d_in[2];
  const float* we_w1 = (const float*)d_in[3];
  const float* we_b1 = (const float*)d_in[4];
  const float* we_w2 = (const float*)d_in[5];
  const float* we_b2 = (const float*)d_in[6];
  const float* wc_w1 = (const float*)d_in[7];
  const float* wc_b1 = (const float*)d_in[8];
  const float* wc_w2 = (const float*)d_in[9];
  const float* wn_w1 = (const float*)d_in[10];
  const float* wn_b1 = (const float*)d_in[11];
  const float* wn_w2 = (const float*)d_in[12];
  const float* wn_b2 = (const float*)d_in[13];
  const float* ln_g  = (const float*)d_in[14];
  const float* ln_b  = (const float*)d_in[15];
  const int* eidx    = (const int*)d_in[16];
  float* out = (float*)d_out;
  char* ws = (char*)d_ws;

  u16* wef    = (u16*)(ws);                      //     73,728
  u16* w1abf  = (u16*)(ws + 73728);              //     65,536
  u16* wnf    = (u16*)(ws + 139264);             //     98,304
  u16* hp     = (u16*)(ws + 237568);             // 25,600,000
  float* m_i  = (float*)(ws + 25837568);         // 25,600,000
  float* xacc = (float*)(ws + 51437568);         //    800,000
  int* degs   = (int*)(ws + 52237568);           //    400,000
  int* curs   = (int*)(ws + 52637568);           //    400,000
  int* rps    = (int*)(ws + 53037568);           //    400,016
  int* pos    = (int*)(ws + 53437584);           //  3,200,000
  int* bsum   = (int*)(ws + 56637584);           //        800
  int* boff   = (int*)(ws + 56638384);           //        816
  u16* m_ij   = (u16*)(ws + 56639200);           // 102,400,000 (end 159,039,200)

  k_wf<<<464, 256, 0, stream>>>(we_w1, we_w2, wc_w1, wn_w1, wn_w2, wef, w1abf, wnf);

  hipFuncSetAttribute(reinterpret_cast<const void*>(k_hp),
                      hipFuncAttributeMaxDynamicSharedMemorySize, 65536);
  k_hp<<<782, 256, 65536, stream>>>(h, w1abf, we_b1, hp);

  hipMemsetAsync(ws + 51437568, 0, 1600000, stream);   // xacc + degs + curs
  k_deg<<<3125, 256, 0, stream>>>(eidx, degs);
  k_bsum<<<196, 256, 0, stream>>>(degs, bsum);
  k_mid<<<1, 128, 0, stream>>>(bsum, boff, rps);
  k_rp<<<196, 256, 0, stream>>>(degs, boff, rps);
  k_scatter<<<3125, 256, 0, stream>>>(eidx, rps, curs, pos);

  hipFuncSetAttribute(reinterpret_cast<const void*>(egnn_edge4),
                      hipFuncAttributeMaxDynamicSharedMemorySize, 159744);
  egnn_edge4<<<256, 1024, 159744, stream>>>(hp, x, ea, eidx, pos, wef,
                                            we_b2, wc_b1, wc_w2, m_ij, xacc, 0);
  k_gather<0><<<12500, 256, 0, stream>>>(m_ij, rps, m_i);
  egnn_edge4<<<256, 1024, 159744, stream>>>(hp, x, ea, eidx, pos, wef,
                                            we_b2, wc_b1, wc_w2, m_ij, xacc, EB_CNT);
  k_gather<1><<<12500, 256, 0, stream>>>(m_ij, rps + (N_CNT + 1), m_i);

  egnn_node2<<<782, 256, 0, stream>>>(h, m_i, wnf, wn_b1, wn_b2, ln_g, ln_b, out);
  egnn_xout<<<196, 256, 0, stream>>>(x, xacc, degs, out + 6400000);
}

// Round 11
// 440.142 us; speedup vs baseline: 1.0769x; 1.0113x over previous
//
#include <hip/hip_runtime.h>

typedef unsigned short u16;
typedef unsigned int u32;
using short8 = __attribute__((ext_vector_type(8))) short;
using f32x4  = __attribute__((ext_vector_type(4))) float;
using u32x4  = __attribute__((ext_vector_type(4))) u32;

#define N_CNT 50000
#define E_CNT 800000
#define EB_CNT 400000   // edges per batch (2 batches)

// RTNE float->bf16 via native __bf16 (lowers to v_cvt_pk_bf16_f32 on gfx950)
__device__ __forceinline__ u16 f2bf(float f) {
  __bf16 b = (__bf16)f;
  return __builtin_bit_cast(u16, b);
}
__device__ __forceinline__ float bf2f(u16 v) {
  u32 u = ((u32)v) << 16;
  return __builtin_bit_cast(float, u);
}
__device__ __forceinline__ short8 pack8(f32x4 v0, f32x4 v1) {
  short8 r;
#pragma unroll
  for (int j = 0; j < 4; ++j) r[j] = (short)f2bf(v0[j]);
#pragma unroll
  for (int j = 0; j < 4; ++j) r[4 + j] = (short)f2bf(v1[j]);
  return r;
}
__device__ __forceinline__ float siluf(float v) {
  return __fdividef(v, 1.f + __expf(-v));
}

// ---------------- prep: weight fragments (MFMA B layout) ----------------
// frag element (tile t, kstep s, lane l, i): B[k=32s+8*(l>>4)+i][n=16t+(l&15)]
// wef:   w1tail [0,4096) | w2f [4096,20480) | wc1f [20480,36864)   (u16 idx)
// w1abf: 32768 u16   (K=128 -> N=256: [W1a | W1b], 16t x 4s)
// wnf:   wn1f 32768 | wn2f 16384
__global__ void k_wf(const float* __restrict__ w1, const float* __restrict__ w2,
                     const float* __restrict__ wc1, const float* __restrict__ wn1,
                     const float* __restrict__ wn2,
                     u16* __restrict__ wef, u16* __restrict__ w1abf,
                     u16* __restrict__ wnf) {
  int idx = blockIdx.x * 256 + threadIdx.x;     // 464*256 == 118784 exact
  int i = idx & 7, l = (idx >> 3) & 63;
  int kb = 8 * (l >> 4) + i;
  int n16 = l & 15;
  if (idx < 4096) {                             // w1tail: 8t x 1s, k = 256..287 of W1
    int t = idx >> 9;
    int k = kb, n = 16 * t + n16;
    wef[idx] = (k < 17) ? f2bf(w1[(256 + k) * 128 + n]) : (u16)0;
  } else if (idx < 20480) {                     // w2f: 8t x 4s
    int u = idx - 4096, rest = u >> 9;
    int s = rest & 3, t = rest >> 2;
    wef[idx] = f2bf(w2[(32 * s + kb) * 128 + 16 * t + n16]);
  } else if (idx < 36864) {                     // wc1f: 8t x 4s
    int u = idx - 20480, rest = u >> 9;
    int s = rest & 3, t = rest >> 2;
    wef[idx] = f2bf(wc1[(32 * s + kb) * 128 + 16 * t + n16]);
  } else if (idx < 69632) {                     // w1abf: 16t x 4s, K=128, N=256
    int u = idx - 36864, rest = u >> 9;
    int s = rest & 3, t = rest >> 2;
    int k = 32 * s + kb, n = 16 * t + n16;
    float v = (n < 128) ? w1[k * 128 + n] : w1[(128 + k) * 128 + (n - 128)];
    w1abf[u] = f2bf(v);
  } else if (idx < 102400) {                    // wn1f: 8t x 8s (K=256)
    int u = idx - 69632, rest = u >> 9;
    int s = rest & 7, t = rest >> 3;
    wnf[u] = f2bf(wn1[(32 * s + kb) * 128 + 16 * t + n16]);
  } else if (idx < 118784) {                    // wn2f: 8t x 4s
    int u = idx - 102400, rest = u >> 9;
    int s = rest & 3, t = rest >> 2;
    wnf[32768 + u] = f2bf(wn2[(32 * s + kb) * 128 + 16 * t + n16]);
  }
}

// ---------------- hp = h @ [W1a|W1b] + [b1|0]  (bf16 [N][256]) ----------------
__global__ __launch_bounds__(256)
void k_hp(const float* __restrict__ h, const u16* __restrict__ w1abf,
          const float* __restrict__ b1v, u16* __restrict__ hp) {
  extern __shared__ char smem[];
  u16* wl = (u16*)smem;
  const int tid = threadIdx.x;
  {
    const u32x4* src = reinterpret_cast<const u32x4*>(w1abf);
    u32x4* dst = reinterpret_cast<u32x4*>(smem);
    for (int i2 = tid; i2 < 4096; i2 += 256) dst[i2] = src[i2];
  }
  __syncthreads();
  const int w = tid >> 6, lane = tid & 63;
  const int g = lane >> 4, c15 = lane & 15;
  float b1r[8];
#pragma unroll
  for (int t = 0; t < 8; ++t) b1r[t] = b1v[t * 16 + c15];

  int wt = blockIdx.x * 4 + w;                   // 782*4 = 3128 >= 3125
  if (wt >= 3125) return;
  int nbase = wt * 16;
  int nr = nbase + c15;
  short8 af[4];
#pragma unroll
  for (int s = 0; s < 4; ++s) {
    const float* p = h + nr * 128 + s * 32 + g * 8;
    af[s] = pack8(*reinterpret_cast<const f32x4*>(p),
                  *reinterpret_cast<const f32x4*>(p + 4));
  }
  f32x4 acc[16];
#pragma unroll
  for (int t = 0; t < 16; ++t) acc[t] = (f32x4){0.f, 0.f, 0.f, 0.f};
#pragma unroll
  for (int s = 0; s < 4; ++s) {
#pragma unroll
    for (int t = 0; t < 16; ++t) {
      short8 bf = *reinterpret_cast<const short8*>(wl + ((t * 4 + s) * 64 + lane) * 8);
      acc[t] = __builtin_amdgcn_mfma_f32_16x16x32_bf16(af[s], bf, acc[t], 0, 0, 0);
    }
  }
#pragma unroll
  for (int t = 0; t < 16; ++t) {
    float bb = (t < 8) ? b1r[t] : 0.f;
    int col = t * 16 + c15;
#pragma unroll
    for (int i = 0; i < 4; ++i)
      hp[(size_t)(nbase + g * 4 + i) * 256 + col] = f2bf(acc[t][i] + bb);
  }
}

// ---------------- CSR build (per-batch) ----------------
__global__ void k_deg(const int* __restrict__ eidx, int* __restrict__ degs) {
  int e = blockIdx.x * 256 + threadIdx.x;       // 3125*256 == 800000
  int b = (e >= EB_CNT) ? 1 : 0;
  atomicAdd(&degs[b * N_CNT + eidx[e]], 1);
}

__global__ void k_bsum(const int* __restrict__ degs, int* __restrict__ bsum) {
  int bid = blockIdx.x;                          // 196 = 2 batches x 98 chunks
  int batch = bid / 98, chunk = bid % 98;
  const int* deg = degs + batch * N_CNT;
  int b0 = chunk * 512 + threadIdx.x;
  int b1 = b0 + 256;
  int v = ((b0 < N_CNT) ? deg[b0] : 0) + ((b1 < N_CNT) ? deg[b1] : 0);
#pragma unroll
  for (int m = 1; m <= 32; m <<= 1) v += __shfl_xor(v, m, 64);
  __shared__ int ws[4];
  if ((threadIdx.x & 63) == 0) ws[threadIdx.x >> 6] = v;
  __syncthreads();
  if (threadIdx.x == 0) bsum[bid] = ws[0] + ws[1] + ws[2] + ws[3];
}

__global__ void k_mid(const int* __restrict__ bsum, int* __restrict__ boff,
                      int* __restrict__ rps) {
  int wv = threadIdx.x >> 6, lane = threadIdx.x & 63;
  if (wv >= 2) return;
  const int* bs = bsum + wv * 98;
  int* bo = boff + wv * 98;
  int carry = 0;
  for (int base = 0; base < 98; base += 64) {
    int idx = base + lane;
    int v = (idx < 98) ? bs[idx] : 0;
    int inc = v;
#pragma unroll
    for (int d = 1; d <= 32; d <<= 1) {
      int u = __shfl_up(inc, d, 64);
      if (lane >= d) inc += u;
    }
    if (idx < 98) bo[idx] = carry + inc - v;
    carry += __shfl(inc, 63, 64);
  }
  if (lane == 0) rps[wv * (N_CNT + 1) + N_CNT] = EB_CNT;
}

__global__ void k_rp(const int* __restrict__ degs, const int* __restrict__ boff,
                     int* __restrict__ rps) {
  int bid = blockIdx.x;
  int batch = bid / 98, chunk = bid % 98;
  const int* deg = degs + batch * N_CNT;
  int* rp = rps + batch * (N_CNT + 1);
  int i0 = chunk * 512 + 2 * threadIdx.x, i1 = i0 + 1;
  int a = (i0 < N_CNT) ? deg[i0] : 0;
  int b = (i1 < N_CNT) ? deg[i1] : 0;
  int s = a + b, lane = threadIdx.x & 63, wv = threadIdx.x >> 6;
  int inc = s;
#pragma unroll
  for (int d = 1; d <= 32; d <<= 1) {
    int u = __shfl_up(inc, d, 64);
    if (lane >= d) inc += u;
  }
  __shared__ int ws2[4];
  if (lane == 63) ws2[wv] = inc;
  __syncthreads();
  int woff = 0;
  for (int k = 0; k < wv; ++k) woff += ws2[k];
  int excl = boff[bid] + woff + inc - s;
  if (i0 < N_CNT) rp[i0] = excl;
  if (i1 < N_CNT) rp[i1] = excl + a;
}

__global__ void k_scatter(const int* __restrict__ eidx, const int* __restrict__ rps,
                          int* __restrict__ curs, int* __restrict__ pos) {
  int e = blockIdx.x * 256 + threadIdx.x;
  int b = (e >= EB_CNT) ? 1 : 0;
  int r = eidx[e];
  int p = atomicAdd(&curs[b * N_CNT + r], 1);
  pos[e] = rps[b * (N_CNT + 1) + r] + p;
}

// ---------------- edge kernel ----------------
// 1024 thr = 16 waves, 16 edges/wave. ALL weight frags in LDS (round-6 proven).
// LDS: w1tf 8192 | w2f 32768 | wc1f 32768 | atail 16x1024 | mbuf 16x4352 = 159744.
__global__ __launch_bounds__(1024, 4)
void egnn_edge4(const u16* __restrict__ hp, const float* __restrict__ xc,
                const float* __restrict__ ea, const int* __restrict__ eidx,
                const int* __restrict__ pos, const u16* __restrict__ wef,
                const float* __restrict__ b2v, const float* __restrict__ bc1v,
                const float* __restrict__ wc2v,
                u16* __restrict__ m_ij, float* __restrict__ x_acc, int ebase0) {
  extern __shared__ char smem[];
  const int tid = threadIdx.x;
  {
    const u32x4* src = reinterpret_cast<const u32x4*>(wef);
    u32x4* dst = reinterpret_cast<u32x4*>(smem);
    for (int i2 = tid; i2 < 4608; i2 += 1024) dst[i2] = src[i2];  // 73728 B
  }
  const int w = tid >> 6, lane = tid & 63;
  const int g = lane >> 4, c15 = lane & 15;
  const int e4 = lane >> 2, q4 = lane & 3;
  const u16* w1tf = (const u16*)smem;             //  8192 B
  const u16* w2f  = (const u16*)(smem + 8192);    // 32768 B
  const u16* wc1f = (const u16*)(smem + 40960);   // 32768 B
  u16* atail = (u16*)(smem + 73728 + w * 1024);   // [16][32] u16, zero-persistent
  u16* mbuf  = (u16*)(smem + 90112 + w * 4352);   // [16][136] u16
  // zero atail once (cols 17..31 stay zero forever)
  *reinterpret_cast<u32x4*>((char*)atail + lane * 16) = (u32x4){0, 0, 0, 0};
  __syncthreads();

  float b2r[8], bc1r[8], wc2r[8];
#pragma unroll
  for (int t = 0; t < 8; ++t) {
    b2r[t]  = b2v[t * 16 + c15];
    bc1r[t] = bc1v[t * 16 + c15];
    wc2r[t] = wc2v[t * 16 + c15];
  }

  for (int bt = blockIdx.x; bt < 1563; bt += gridDim.x) {
    int wt = bt * 16 + w;
    if (wt >= 25000) continue;
    const int eb = ebase0 + wt * 16;
    // geometry (lanes 0..15)
    int r_v = 0, c_v = 0, p_v = 0;
    if (lane < 16) {
      int gi = eb + lane;
      r_v = eidx[gi]; c_v = eidx[E_CNT + gi]; p_v = pos[gi];
      float d0 = xc[3 * r_v + 0] - xc[3 * c_v + 0];
      float d1 = xc[3 * r_v + 1] - xc[3 * c_v + 1];
      float d2 = xc[3 * r_v + 2] - xc[3 * c_v + 2];
      float dsq = d0 * d0 + d1 * d1 + d2 * d2;
      f32x4 cd = {d0, d1, d2, dsq};
      *reinterpret_cast<f32x4*>(mbuf + lane * 136 + 128) = cd;
    }
    int re = __shfl(r_v, c15, 64);
    int ce = __shfl(c_v, c15, 64);
    int pc = __shfl(p_v, c15, 64);
    // hp gathers in A-fragment pattern (row = c15's edge, cols 32s+8g+j)
    short8 ga[4], gb[4];
    {
      const u16* pa = hp + (size_t)re * 256 + g * 8;
      const u16* pb = hp + (size_t)ce * 256 + 128 + g * 8;
#pragma unroll
      for (int s = 0; s < 4; ++s) ga[s] = *reinterpret_cast<const short8*>(pa + s * 32);
#pragma unroll
      for (int s = 0; s < 4; ++s) gb[s] = *reinterpret_cast<const short8*>(pb + s * 32);
    }
    // tail A-tile: [dsq, ea0..15, 0(persistent)..]
    {
      u16* row = atail + e4 * 32;
      f32x4 eav = *reinterpret_cast<const f32x4*>(ea + (size_t)(eb + e4) * 16 + q4 * 4);
#pragma unroll
      for (int jj = 0; jj < 4; ++jj)
        row[1 + q4 * 4 + jj] = f2bf(eav[jj]);
      if (q4 == 0) {
        float dq = reinterpret_cast<const float*>(mbuf + e4 * 136 + 128)[3];
        row[0] = f2bf(dq);
      }
    }
    // tail MFMA (K=32), B from LDS
    short8 af8 = *reinterpret_cast<const short8*>(atail + c15 * 32 + g * 8);
    f32x4 acc[8];
#pragma unroll
    for (int t = 0; t < 8; ++t) acc[t] = (f32x4){0.f, 0.f, 0.f, 0.f};
#pragma unroll
    for (int t = 0; t < 8; ++t) {
      short8 bf = *reinterpret_cast<const short8*>(w1tf + (t * 64 + lane) * 8);
      acc[t] = __builtin_amdgcn_mfma_f32_16x16x32_bf16(af8, bf, acc[t], 0, 0, 0);
    }
    // tail C -> mbuf (raw, no bias/silu)
#pragma unroll
    for (int t = 0; t < 8; ++t) {
      int col = t * 16 + c15;
#pragma unroll
      for (int i = 0; i < 4; ++i)
        mbuf[(g * 4 + i) * 136 + col] = f2bf(acc[t][i]);
    }
    // combine in-register -> layer-2 A fragments (no m1 LDS round-trip)
    short8 a2[4];
#pragma unroll
    for (int s = 0; s < 4; ++s) {
      short8 tl = *reinterpret_cast<const short8*>(mbuf + c15 * 136 + s * 32 + g * 8);
      short8 o;
#pragma unroll
      for (int j = 0; j < 8; ++j) {
        float v = bf2f((u16)tl[j]) + bf2f((u16)ga[s][j]) + bf2f((u16)gb[s][j]);
        o[j] = (short)f2bf(siluf(v));
      }
      a2[s] = o;
    }
    // layer 2: m1 @ we_w2 (B from LDS)
    f32x4 acc2[8];
#pragma unroll
    for (int t = 0; t < 8; ++t) acc2[t] = (f32x4){0.f, 0.f, 0.f, 0.f};
#pragma unroll
    for (int s = 0; s < 4; ++s) {
#pragma unroll
      for (int t = 0; t < 8; ++t) {
        short8 bf = *reinterpret_cast<const short8*>(w2f + ((t * 4 + s) * 64 + lane) * 8);
        acc2[t] = __builtin_amdgcn_mfma_f32_16x16x32_bf16(a2[s], bf, acc2[t], 0, 0, 0);
      }
    }
    // m2 C -> mbuf (C->A transpose for m_ij + coord input)
#pragma unroll
    for (int t = 0; t < 8; ++t) {
      int col = t * 16 + c15;
#pragma unroll
      for (int i = 0; i < 4; ++i)
        mbuf[(g * 4 + i) * 136 + col] = f2bf(siluf(acc2[t][i] + b2r[t]));
    }
    // a3 + stream to m_ij[slot]
    short8 a3[4];
#pragma unroll
    for (int s = 0; s < 4; ++s) {
      a3[s] = *reinterpret_cast<const short8*>(mbuf + c15 * 136 + s * 32 + g * 8);
      *reinterpret_cast<short8*>(m_ij + (size_t)pc * 128 + s * 32 + g * 8) = a3[s];
    }
    // coord MLP (B from LDS)
    f32x4 acc3[8];
#pragma unroll
    for (int t = 0; t < 8; ++t) acc3[t] = (f32x4){0.f, 0.f, 0.f, 0.f};
#pragma unroll
    for (int s = 0; s < 4; ++s) {
#pragma unroll
      for (int t = 0; t < 8; ++t) {
        short8 bf = *reinterpret_cast<const short8*>(wc1f + ((t * 4 + s) * 64 + lane) * 8);
        acc3[t] = __builtin_amdgcn_mfma_f32_16x16x32_bf16(a3[s], bf, acc3[t], 0, 0, 0);
      }
    }
    float p4[4] = {0.f, 0.f, 0.f, 0.f};
#pragma unroll
    for (int t = 0; t < 8; ++t)
#pragma unroll
      for (int i = 0; i < 4; ++i)
        p4[i] += siluf(acc3[t][i] + bc1r[t]) * wc2r[t];
#pragma unroll
    for (int m = 1; m <= 8; m <<= 1) {
#pragma unroll
      for (int i = 0; i < 4; ++i) p4[i] += __shfl_xor(p4[i], m, 64);
    }
    int rr[4];
#pragma unroll
    for (int i = 0; i < 4; ++i) rr[i] = __shfl(r_v, g * 4 + i, 64);
    if (c15 == 0) {
#pragma unroll
      for (int i = 0; i < 4; ++i) {
        f32x4 cd = *reinterpret_cast<const f32x4*>(mbuf + (g * 4 + i) * 136 + 128);
        float fac = rsqrtf(cd[3] + 1e-8f) * tanhf(p4[i]);
        atomicAdd(&x_acc[rr[i] * 4 + 0], cd[0] * fac);
        atomicAdd(&x_acc[rr[i] * 4 + 1], cd[1] * fac);
        atomicAdd(&x_acc[rr[i] * 4 + 2], cd[2] * fac);
      }
    }
  }
}

// ---------------- gather: m_i[n] (bf16) = sum of contiguous m_ij slot rows ----------------
template <int ACC>
__global__ __launch_bounds__(256)
void k_gather(const u16* __restrict__ m_ij, const int* __restrict__ rp,
              u16* __restrict__ m_i) {
  const int tid = threadIdx.x, w = tid >> 6, lane = tid & 63;
  const int grp = lane >> 4, c16 = lane & 15;
  int node = blockIdx.x * 4 + w;                 // 12500*4 == 50000
  int beg = rp[node], end = rp[node + 1];
  float a[8] = {0.f, 0.f, 0.f, 0.f, 0.f, 0.f, 0.f, 0.f};
  for (int j = beg + grp; j < end; j += 4) {
    short8 v = *reinterpret_cast<const short8*>(m_ij + (size_t)j * 128 + c16 * 8);
#pragma unroll
    for (int k = 0; k < 8; ++k) a[k] += bf2f((u16)v[k]);
  }
#pragma unroll
  for (int k = 0; k < 8; ++k) {
    a[k] += __shfl_xor(a[k], 16, 64);
    a[k] += __shfl_xor(a[k], 32, 64);
  }
  if (grp == 0) {
    u16* dst = m_i + (size_t)node * 128 + c16 * 8;
    if (ACC) {
      short8 o = *reinterpret_cast<const short8*>(dst);
#pragma unroll
      for (int k = 0; k < 8; ++k) a[k] += bf2f((u16)o[k]);
    }
    short8 v;
#pragma unroll
    for (int k = 0; k < 8; ++k) v[k] = (short)f2bf(a[k]);
    *reinterpret_cast<short8*>(dst) = v;
  }
}

// ---------------- node kernel (m_i read as bf16 A-fragments directly) ----------------
__global__ __launch_bounds__(256)
void egnn_node2(const float* __restrict__ h, const u16* __restrict__ m_i,
                const u16* __restrict__ wnf,
                const float* __restrict__ bn1, const float* __restrict__ bn2,
                const float* __restrict__ lng, const float* __restrict__ lnb,
                float* __restrict__ h_out) {
  __shared__ u16 mbuf_all[4][2176];
  const int tid = threadIdx.x, w = tid >> 6, lane = tid & 63;
  const int g = lane >> 4, c15 = lane & 15;
  u16* mbuf = mbuf_all[w];
  const u16* wn1f = wnf;
  const u16* wn2f = wnf + 32768;

  float bn1r[8], bn2r[8], lngr[8], lnbr[8];
#pragma unroll
  for (int t = 0; t < 8; ++t) {
    bn1r[t] = bn1[t * 16 + c15];
    bn2r[t] = bn2[t * 16 + c15];
    lngr[t] = lng[t * 16 + c15];
    lnbr[t] = lnb[t * 16 + c15];
  }

  int wt = blockIdx.x * 4 + w;                   // 782*4 = 3128 >= 3125
  if (wt >= 3125) return;
  int nbase = wt * 16;
  int nr = nbase + c15;
  short8 af[8];
#pragma unroll
  for (int s = 0; s < 4; ++s) {
    const float* p = h + nr * 128 + s * 32 + g * 8;
    af[s] = pack8(*reinterpret_cast<const f32x4*>(p),
                  *reinterpret_cast<const f32x4*>(p + 4));
  }
#pragma unroll
  for (int s = 0; s < 4; ++s)
    af[4 + s] = *reinterpret_cast<const short8*>(m_i + (size_t)nr * 128 + s * 32 + g * 8);
  f32x4 acc[8];
#pragma unroll
  for (int t = 0; t < 8; ++t) acc[t] = (f32x4){0.f, 0.f, 0.f, 0.f};
#pragma unroll
  for (int s = 0; s < 8; ++s) {
#pragma unroll
    for (int t = 0; t < 8; ++t) {
      short8 bf = *reinterpret_cast<const short8*>(wn1f + ((t * 8 + s) * 64 + lane) * 8);
      acc[t] = __builtin_amdgcn_mfma_f32_16x16x32_bf16(af[s], bf, acc[t], 0, 0, 0);
    }
  }
#pragma unroll
  for (int t = 0; t < 8; ++t) {
    int col = t * 16 + c15;
#pragma unroll
    for (int i = 0; i < 4; ++i)
      mbuf[(g * 4 + i) * 136 + col] = f2bf(siluf(acc[t][i] + bn1r[t]));
  }
  short8 a2[4];
#pragma unroll
  for (int s = 0; s < 4; ++s)
    a2[s] = *reinterpret_cast<const short8*>(mbuf + c15 * 136 + s * 32 + g * 8);
  f32x4 acc2[8];
#pragma unroll
  for (int t = 0; t < 8; ++t) acc2[t] = (f32x4){0.f, 0.f, 0.f, 0.f};
#pragma unroll
  for (int s = 0; s < 4; ++s) {
#pragma unroll
    for (int t = 0; t < 8; ++t) {
      short8 bf = *reinterpret_cast<const short8*>(wn2f + ((t * 4 + s) * 64 + lane) * 8);
      acc2[t] = __builtin_amdgcn_mfma_f32_16x16x32_bf16(a2[s], bf, acc2[t], 0, 0, 0);
    }
  }
  float vres[8][4];
  float s1[4] = {0.f, 0.f, 0.f, 0.f}, s2[4] = {0.f, 0.f, 0.f, 0.f};
#pragma unroll
  for (int t = 0; t < 8; ++t)
#pragma unroll
    for (int i = 0; i < 4; ++i) {
      int n = nbase + g * 4 + i;
      float v = acc2[t][i] + bn2r[t] + h[n * 128 + t * 16 + c15];
      vres[t][i] = v; s1[i] += v; s2[i] += v * v;
    }
#pragma unroll
  for (int m = 1; m <= 8; m <<= 1) {
#pragma unroll
    for (int i = 0; i < 4; ++i) {
      s1[i] += __shfl_xor(s1[i], m, 64);
      s2[i] += __shfl_xor(s2[i], m, 64);
    }
  }
  float mu[4], rstd[4];
#pragma unroll
  for (int i = 0; i < 4; ++i) {
    mu[i] = s1[i] * (1.0f / 128.0f);
    float var = s2[i] * (1.0f / 128.0f) - mu[i] * mu[i];
    rstd[i] = rsqrtf(var + 1e-5f);
  }
#pragma unroll
  for (int t = 0; t < 8; ++t)
#pragma unroll
    for (int i = 0; i < 4; ++i) {
      int n = nbase + g * 4 + i;
      h_out[n * 128 + t * 16 + c15] =
          (vres[t][i] - mu[i]) * rstd[i] * lngr[t] + lnbr[t];
    }
}

// ---------------- x_out ----------------
__global__ void egnn_xout(const float* __restrict__ x, const float* __restrict__ x_acc,
                          const int* __restrict__ degs, float* __restrict__ xo) {
  int n = blockIdx.x * 256 + threadIdx.x;
  if (n < N_CNT) {
    float dg = fmaxf((float)(degs[n] + degs[N_CNT + n]), 1.0f);
    xo[n * 3 + 0] = x[n * 3 + 0] + x_acc[n * 4 + 0] / dg;
    xo[n * 3 + 1] = x[n * 3 + 1] + x_acc[n * 4 + 1] / dg;
    xo[n * 3 + 2] = x[n * 3 + 2] + x_acc[n * 4 + 2] / dg;
  }
}

extern "C" void kernel_launch(void* const* d_in, const int* in_sizes, int n_in,
                              void* d_out, int out_size, void* d_ws, size_t ws_size,
                              hipStream_t stream) {
  const float* h     = (const float*)d_in[0];
  const float* x     = (const float*)d_in[1];
  const float* ea    = (const float*)d_in[2];
  const float* we_w1 = (const float*)d_in[3];
  const float* we_b1 = (const float*)d_in[4];
  const float* we_w2 = (const float*)d_in[5];
  const float* we_b2 = (const float*)d_in[6];
  const float* wc_w1 = (const float*)d_in[7];
  const float* wc_b1 = (const float*)d_in[8];
  const float* wc_w2 = (const float*)d_in[9];
  const float* wn_w1 = (const float*)d_in[10];
  const float* wn_b1 = (const float*)d_in[11];
  const float* wn_w2 = (const float*)d_in[12];
  const float* wn_b2 = (const float*)d_in[13];
  const float* ln_g  = (const float*)d_in[14];
  const float* ln_b  = (const float*)d_in[15];
  const int* eidx    = (const int*)d_in[16];
  float* out = (float*)d_out;
  char* ws = (char*)d_ws;

  u16* wef    = (u16*)(ws);                      //     73,728
  u16* w1abf  = (u16*)(ws + 73728);              //     65,536
  u16* wnf    = (u16*)(ws + 139264);             //     98,304
  u16* hp     = (u16*)(ws + 237568);             // 25,600,000
  u16* m_i    = (u16*)(ws + 25837568);           // 12,800,000 (bf16; region oversized, offsets unchanged)
  float* xacc = (float*)(ws + 51437568);         //    800,000
  int* degs   = (int*)(ws + 52237568);           //    400,000
  int* curs   = (int*)(ws + 52637568);           //    400,000
  int* rps    = (int*)(ws + 53037568);           //    400,016
  int* pos    = (int*)(ws + 53437584);           //  3,200,000
  int* bsum   = (int*)(ws + 56637584);           //        800
  int* boff   = (int*)(ws + 56638384);           //        816
  u16* m_ij   = (u16*)(ws + 56639200);           // 102,400,000 (end 159,039,200)

  k_wf<<<464, 256, 0, stream>>>(we_w1, we_w2, wc_w1, wn_w1, wn_w2, wef, w1abf, wnf);

  hipFuncSetAttribute(reinterpret_cast<const void*>(k_hp),
                      hipFuncAttributeMaxDynamicSharedMemorySize, 65536);
  k_hp<<<782, 256, 65536, stream>>>(h, w1abf, we_b1, hp);

  hipMemsetAsync(ws + 51437568, 0, 1600000, stream);   // xacc + degs + curs
  k_deg<<<3125, 256, 0, stream>>>(eidx, degs);
  k_bsum<<<196, 256, 0, stream>>>(degs, bsum);
  k_mid<<<1, 128, 0, stream>>>(bsum, boff, rps);
  k_rp<<<196, 256, 0, stream>>>(degs, boff, rps);
  k_scatter<<<3125, 256, 0, stream>>>(eidx, rps, curs, pos);

  hipFuncSetAttribute(reinterpret_cast<const void*>(egnn_edge4),
                      hipFuncAttributeMaxDynamicSharedMemorySize, 159744);
  egnn_edge4<<<256, 1024, 159744, stream>>>(hp, x, ea, eidx, pos, wef,
                                            we_b2, wc_b1, wc_w2, m_ij, xacc, 0);
  k_gather<0><<<12500, 256, 0, stream>>>(m_ij, rps, m_i);
  egnn_edge4<<<256, 1024, 159744, stream>>>(hp, x, ea, eidx, pos, wef,
                                            we_b2, wc_b1, wc_w2, m_ij, xacc, EB_CNT);
  k_gather<1><<<12500, 256, 0, stream>>>(m_ij, rps + (N_CNT + 1), m_i);

  egnn_node2<<<782, 256, 0, stream>>>(h, m_i, wnf, wn_b1, wn_b2, ln_g, ln_b, out);
  egnn_xout<<<196, 256, 0, stream>>>(x, xacc, degs, out + 6400000);
}

// Round 12
// 419.552 us; speedup vs baseline: 1.1298x; 1.0491x over previous
//
#include <hip/hip_runtime.h>

typedef unsigned short u16;
typedef unsigned int u32;
using short8 = __attribute__((ext_vector_type(8))) short;
using f32x4  = __attribute__((ext_vector_type(4))) float;
using u32x4  = __attribute__((ext_vector_type(4))) u32;

#define N_CNT 50000
#define E_CNT 800000

// RTNE float->bf16 via native __bf16 (lowers to v_cvt_pk_bf16_f32 on gfx950)
__device__ __forceinline__ u16 f2bf(float f) {
  __bf16 b = (__bf16)f;
  return __builtin_bit_cast(u16, b);
}
__device__ __forceinline__ float bf2f(u16 v) {
  u32 u = ((u32)v) << 16;
  return __builtin_bit_cast(float, u);
}
__device__ __forceinline__ short8 pack8(f32x4 v0, f32x4 v1) {
  short8 r;
#pragma unroll
  for (int j = 0; j < 4; ++j) r[j] = (short)f2bf(v0[j]);
#pragma unroll
  for (int j = 0; j < 4; ++j) r[4 + j] = (short)f2bf(v1[j]);
  return r;
}
__device__ __forceinline__ float siluf(float v) {
  return __fdividef(v, 1.f + __expf(-v));
}

// ---------------- prep: weight fragments (MFMA B layout) ----------------
// frag element (tile t, kstep s, lane l, i): B[k=32s+8*(l>>4)+i][n=16t+(l&15)]
// wef:   w1tail [0,4096) | w2f [4096,20480) | wc1f [20480,36864)   (u16 idx)
// w1abf: 32768 u16   (K=128 -> N=256: [W1a | W1b], 16t x 4s)
// wnf:   wn1f 32768 | wn2f 16384
__global__ void k_wf(const float* __restrict__ w1, const float* __restrict__ w2,
                     const float* __restrict__ wc1, const float* __restrict__ wn1,
                     const float* __restrict__ wn2,
                     u16* __restrict__ wef, u16* __restrict__ w1abf,
                     u16* __restrict__ wnf) {
  int idx = blockIdx.x * 256 + threadIdx.x;     // 464*256 == 118784 exact
  int i = idx & 7, l = (idx >> 3) & 63;
  int kb = 8 * (l >> 4) + i;
  int n16 = l & 15;
  if (idx < 4096) {                             // w1tail: 8t x 1s, k = 256..287 of W1
    int t = idx >> 9;
    int k = kb, n = 16 * t + n16;
    wef[idx] = (k < 17) ? f2bf(w1[(256 + k) * 128 + n]) : (u16)0;
  } else if (idx < 20480) {                     // w2f: 8t x 4s
    int u = idx - 4096, rest = u >> 9;
    int s = rest & 3, t = rest >> 2;
    wef[idx] = f2bf(w2[(32 * s + kb) * 128 + 16 * t + n16]);
  } else if (idx < 36864) {                     // wc1f: 8t x 4s
    int u = idx - 20480, rest = u >> 9;
    int s = rest & 3, t = rest >> 2;
    wef[idx] = f2bf(wc1[(32 * s + kb) * 128 + 16 * t + n16]);
  } else if (idx < 69632) {                     // w1abf: 16t x 4s, K=128, N=256
    int u = idx - 36864, rest = u >> 9;
    int s = rest & 3, t = rest >> 2;
    int k = 32 * s + kb, n = 16 * t + n16;
    float v = (n < 128) ? w1[k * 128 + n] : w1[(128 + k) * 128 + (n - 128)];
    w1abf[u] = f2bf(v);
  } else if (idx < 102400) {                    // wn1f: 8t x 8s (K=256)
    int u = idx - 69632, rest = u >> 9;
    int s = rest & 7, t = rest >> 3;
    wnf[u] = f2bf(wn1[(32 * s + kb) * 128 + 16 * t + n16]);
  } else if (idx < 118784) {                    // wn2f: 8t x 4s
    int u = idx - 102400, rest = u >> 9;
    int s = rest & 3, t = rest >> 2;
    wnf[32768 + u] = f2bf(wn2[(32 * s + kb) * 128 + 16 * t + n16]);
  }
}

// ---------------- hp = h @ [W1a|W1b] + [b1|0]  (bf16 [N][256]) ----------------
__global__ __launch_bounds__(256)
void k_hp(const float* __restrict__ h, const u16* __restrict__ w1abf,
          const float* __restrict__ b1v, u16* __restrict__ hp) {
  extern __shared__ char smem[];
  u16* wl = (u16*)smem;
  const int tid = threadIdx.x;
  {
    const u32x4* src = reinterpret_cast<const u32x4*>(w1abf);
    u32x4* dst = reinterpret_cast<u32x4*>(smem);
    for (int i2 = tid; i2 < 4096; i2 += 256) dst[i2] = src[i2];
  }
  __syncthreads();
  const int w = tid >> 6, lane = tid & 63;
  const int g = lane >> 4, c15 = lane & 15;
  float b1r[8];
#pragma unroll
  for (int t = 0; t < 8; ++t) b1r[t] = b1v[t * 16 + c15];

  int wt = blockIdx.x * 4 + w;                   // 782*4 = 3128 >= 3125
  if (wt >= 3125) return;
  int nbase = wt * 16;
  int nr = nbase + c15;
  short8 af[4];
#pragma unroll
  for (int s = 0; s < 4; ++s) {
    const float* p = h + nr * 128 + s * 32 + g * 8;
    af[s] = pack8(*reinterpret_cast<const f32x4*>(p),
                  *reinterpret_cast<const f32x4*>(p + 4));
  }
  f32x4 acc[16];
#pragma unroll
  for (int t = 0; t < 16; ++t) acc[t] = (f32x4){0.f, 0.f, 0.f, 0.f};
#pragma unroll
  for (int s = 0; s < 4; ++s) {
#pragma unroll
    for (int t = 0; t < 16; ++t) {
      short8 bf = *reinterpret_cast<const short8*>(wl + ((t * 4 + s) * 64 + lane) * 8);
      acc[t] = __builtin_amdgcn_mfma_f32_16x16x32_bf16(af[s], bf, acc[t], 0, 0, 0);
    }
  }
#pragma unroll
  for (int t = 0; t < 16; ++t) {
    float bb = (t < 8) ? b1r[t] : 0.f;
    int col = t * 16 + c15;
#pragma unroll
    for (int i = 0; i < 4; ++i)
      hp[(size_t)(nbase + g * 4 + i) * 256 + col] = f2bf(acc[t][i] + bb);
  }
}

// ---------------- CSR build (per-batch; EB = batch-0 edge count) ----------------
__global__ void k_deg(const int* __restrict__ eidx, int* __restrict__ degs, int EB) {
  int e = blockIdx.x * 256 + threadIdx.x;       // 3125*256 == 800000
  int b = (e >= EB) ? 1 : 0;
  atomicAdd(&degs[b * N_CNT + eidx[e]], 1);
}

__global__ void k_bsum(const int* __restrict__ degs, int* __restrict__ bsum) {
  int bid = blockIdx.x;                          // 196 = 2 batches x 98 chunks
  int batch = bid / 98, chunk = bid % 98;
  const int* deg = degs + batch * N_CNT;
  int b0 = chunk * 512 + threadIdx.x;
  int b1 = b0 + 256;
  int v = ((b0 < N_CNT) ? deg[b0] : 0) + ((b1 < N_CNT) ? deg[b1] : 0);
#pragma unroll
  for (int m = 1; m <= 32; m <<= 1) v += __shfl_xor(v, m, 64);
  __shared__ int ws[4];
  if ((threadIdx.x & 63) == 0) ws[threadIdx.x >> 6] = v;
  __syncthreads();
  if (threadIdx.x == 0) bsum[bid] = ws[0] + ws[1] + ws[2] + ws[3];
}

__global__ void k_mid(const int* __restrict__ bsum, int* __restrict__ boff,
                      int* __restrict__ rps, int e0, int e1) {
  int wv = threadIdx.x >> 6, lane = threadIdx.x & 63;
  if (wv >= 2) return;
  const int* bs = bsum + wv * 98;
  int* bo = boff + wv * 98;
  int carry = 0;
  for (int base = 0; base < 98; base += 64) {
    int idx = base + lane;
    int v = (idx < 98) ? bs[idx] : 0;
    int inc = v;
#pragma unroll
    for (int d = 1; d <= 32; d <<= 1) {
      int u = __shfl_up(inc, d, 64);
      if (lane >= d) inc += u;
    }
    if (idx < 98) bo[idx] = carry + inc - v;
    carry += __shfl(inc, 63, 64);
  }
  if (lane == 0) rps[wv * (N_CNT + 1) + N_CNT] = (wv == 0) ? e0 : e1;
}

__global__ void k_rp(const int* __restrict__ degs, const int* __restrict__ boff,
                     int* __restrict__ rps) {
  int bid = blockIdx.x;
  int batch = bid / 98, chunk = bid % 98;
  const int* deg = degs + batch * N_CNT;
  int* rp = rps + batch * (N_CNT + 1);
  int i0 = chunk * 512 + 2 * threadIdx.x, i1 = i0 + 1;
  int a = (i0 < N_CNT) ? deg[i0] : 0;
  int b = (i1 < N_CNT) ? deg[i1] : 0;
  int s = a + b, lane = threadIdx.x & 63, wv = threadIdx.x >> 6;
  int inc = s;
#pragma unroll
  for (int d = 1; d <= 32; d <<= 1) {
    int u = __shfl_up(inc, d, 64);
    if (lane >= d) inc += u;
  }
  __shared__ int ws2[4];
  if (lane == 63) ws2[wv] = inc;
  __syncthreads();
  int woff = 0;
  for (int k = 0; k < wv; ++k) woff += ws2[k];
  int excl = boff[bid] + woff + inc - s;
  if (i0 < N_CNT) rp[i0] = excl;
  if (i1 < N_CNT) rp[i1] = excl + a;
}

__global__ void k_scatter(const int* __restrict__ eidx, const int* __restrict__ rps,
                          int* __restrict__ curs, int* __restrict__ pos, int EB) {
  int e = blockIdx.x * 256 + threadIdx.x;
  int b = (e >= EB) ? 1 : 0;
  int r = eidx[e];
  int p = atomicAdd(&curs[b * N_CNT + r], 1);
  pos[e] = rps[b * (N_CNT + 1) + r] + p;
}

// ---------------- edge kernel ----------------
// 1024 thr = 16 waves, 16 edges/wave. ALL weight frags in LDS (round-6 proven).
// LDS: w1tf 8192 | w2f 32768 | wc1f 32768 | atail 16x1024 | mbuf 16x4352 = 159744.
// nbt = block-tile count, nwt = wave-tile count (2-batch: 1563/25000; 1-batch: 3125/50000).
__global__ __launch_bounds__(1024, 4)
void egnn_edge4(const u16* __restrict__ hp, const float* __restrict__ xc,
                const float* __restrict__ ea, const int* __restrict__ eidx,
                const int* __restrict__ pos, const u16* __restrict__ wef,
                const float* __restrict__ b2v, const float* __restrict__ bc1v,
                const float* __restrict__ wc2v,
                u16* __restrict__ m_ij, float* __restrict__ x_acc,
                int ebase0, int nbt, int nwt) {
  extern __shared__ char smem[];
  const int tid = threadIdx.x;
  {
    const u32x4* src = reinterpret_cast<const u32x4*>(wef);
    u32x4* dst = reinterpret_cast<u32x4*>(smem);
    for (int i2 = tid; i2 < 4608; i2 += 1024) dst[i2] = src[i2];  // 73728 B
  }
  const int w = tid >> 6, lane = tid & 63;
  const int g = lane >> 4, c15 = lane & 15;
  const int e4 = lane >> 2, q4 = lane & 3;
  const u16* w1tf = (const u16*)smem;             //  8192 B
  const u16* w2f  = (const u16*)(smem + 8192);    // 32768 B
  const u16* wc1f = (const u16*)(smem + 40960);   // 32768 B
  u16* atail = (u16*)(smem + 73728 + w * 1024);   // [16][32] u16, zero-persistent
  u16* mbuf  = (u16*)(smem + 90112 + w * 4352);   // [16][136] u16
  // zero atail once (cols 17..31 stay zero forever)
  *reinterpret_cast<u32x4*>((char*)atail + lane * 16) = (u32x4){0, 0, 0, 0};
  __syncthreads();

  float b2r[8], bc1r[8], wc2r[8];
#pragma unroll
  for (int t = 0; t < 8; ++t) {
    b2r[t]  = b2v[t * 16 + c15];
    bc1r[t] = bc1v[t * 16 + c15];
    wc2r[t] = wc2v[t * 16 + c15];
  }

  for (int bt = blockIdx.x; bt < nbt; bt += gridDim.x) {
    int wt = bt * 16 + w;
    if (wt >= nwt) continue;
    const int eb = ebase0 + wt * 16;
    // geometry (lanes 0..15)
    int r_v = 0, c_v = 0, p_v = 0;
    if (lane < 16) {
      int gi = eb + lane;
      r_v = eidx[gi]; c_v = eidx[E_CNT + gi]; p_v = pos[gi];
      float d0 = xc[3 * r_v + 0] - xc[3 * c_v + 0];
      float d1 = xc[3 * r_v + 1] - xc[3 * c_v + 1];
      float d2 = xc[3 * r_v + 2] - xc[3 * c_v + 2];
      float dsq = d0 * d0 + d1 * d1 + d2 * d2;
      f32x4 cd = {d0, d1, d2, dsq};
      *reinterpret_cast<f32x4*>(mbuf + lane * 136 + 128) = cd;
    }
    int re = __shfl(r_v, c15, 64);
    int ce = __shfl(c_v, c15, 64);
    int pc = __shfl(p_v, c15, 64);
    // hp gathers in A-fragment pattern (row = c15's edge, cols 32s+8g+j)
    short8 ga[4], gb[4];
    {
      const u16* pa = hp + (size_t)re * 256 + g * 8;
      const u16* pb = hp + (size_t)ce * 256 + 128 + g * 8;
#pragma unroll
      for (int s = 0; s < 4; ++s) ga[s] = *reinterpret_cast<const short8*>(pa + s * 32);
#pragma unroll
      for (int s = 0; s < 4; ++s) gb[s] = *reinterpret_cast<const short8*>(pb + s * 32);
    }
    // tail A-tile: [dsq, ea0..15, 0(persistent)..]
    {
      u16* row = atail + e4 * 32;
      f32x4 eav = *reinterpret_cast<const f32x4*>(ea + (size_t)(eb + e4) * 16 + q4 * 4);
#pragma unroll
      for (int jj = 0; jj < 4; ++jj)
        row[1 + q4 * 4 + jj] = f2bf(eav[jj]);
      if (q4 == 0) {
        float dq = reinterpret_cast<const float*>(mbuf + e4 * 136 + 128)[3];
        row[0] = f2bf(dq);
      }
    }
    // tail MFMA (K=32), B from LDS
    short8 af8 = *reinterpret_cast<const short8*>(atail + c15 * 32 + g * 8);
    f32x4 acc[8];
#pragma unroll
    for (int t = 0; t < 8; ++t) acc[t] = (f32x4){0.f, 0.f, 0.f, 0.f};
#pragma unroll
    for (int t = 0; t < 8; ++t) {
      short8 bf = *reinterpret_cast<const short8*>(w1tf + (t * 64 + lane) * 8);
      acc[t] = __builtin_amdgcn_mfma_f32_16x16x32_bf16(af8, bf, acc[t], 0, 0, 0);
    }
    // tail C -> mbuf (raw, no bias/silu)
#pragma unroll
    for (int t = 0; t < 8; ++t) {
      int col = t * 16 + c15;
#pragma unroll
      for (int i = 0; i < 4; ++i)
        mbuf[(g * 4 + i) * 136 + col] = f2bf(acc[t][i]);
    }
    // combine in-register -> layer-2 A fragments (no m1 LDS round-trip)
    short8 a2[4];
#pragma unroll
    for (int s = 0; s < 4; ++s) {
      short8 tl = *reinterpret_cast<const short8*>(mbuf + c15 * 136 + s * 32 + g * 8);
      short8 o;
#pragma unroll
      for (int j = 0; j < 8; ++j) {
        float v = bf2f((u16)tl[j]) + bf2f((u16)ga[s][j]) + bf2f((u16)gb[s][j]);
        o[j] = (short)f2bf(siluf(v));
      }
      a2[s] = o;
    }
    // layer 2: m1 @ we_w2 (B from LDS)
    f32x4 acc2[8];
#pragma unroll
    for (int t = 0; t < 8; ++t) acc2[t] = (f32x4){0.f, 0.f, 0.f, 0.f};
#pragma unroll
    for (int s = 0; s < 4; ++s) {
#pragma unroll
      for (int t = 0; t < 8; ++t) {
        short8 bf = *reinterpret_cast<const short8*>(w2f + ((t * 4 + s) * 64 + lane) * 8);
        acc2[t] = __builtin_amdgcn_mfma_f32_16x16x32_bf16(a2[s], bf, acc2[t], 0, 0, 0);
      }
    }
    // m2 C -> mbuf (C->A transpose for m_ij + coord input)
#pragma unroll
    for (int t = 0; t < 8; ++t) {
      int col = t * 16 + c15;
#pragma unroll
      for (int i = 0; i < 4; ++i)
        mbuf[(g * 4 + i) * 136 + col] = f2bf(siluf(acc2[t][i] + b2r[t]));
    }
    // a3 + stream to m_ij[slot]
    short8 a3[4];
#pragma unroll
    for (int s = 0; s < 4; ++s) {
      a3[s] = *reinterpret_cast<const short8*>(mbuf + c15 * 136 + s * 32 + g * 8);
      *reinterpret_cast<short8*>(m_ij + (size_t)pc * 128 + s * 32 + g * 8) = a3[s];
    }
    // coord MLP (B from LDS)
    f32x4 acc3[8];
#pragma unroll
    for (int t = 0; t < 8; ++t) acc3[t] = (f32x4){0.f, 0.f, 0.f, 0.f};
#pragma unroll
    for (int s = 0; s < 4; ++s) {
#pragma unroll
      for (int t = 0; t < 8; ++t) {
        short8 bf = *reinterpret_cast<const short8*>(wc1f + ((t * 4 + s) * 64 + lane) * 8);
        acc3[t] = __builtin_amdgcn_mfma_f32_16x16x32_bf16(a3[s], bf, acc3[t], 0, 0, 0);
      }
    }
    float p4[4] = {0.f, 0.f, 0.f, 0.f};
#pragma unroll
    for (int t = 0; t < 8; ++t)
#pragma unroll
      for (int i = 0; i < 4; ++i)
        p4[i] += siluf(acc3[t][i] + bc1r[t]) * wc2r[t];
#pragma unroll
    for (int m = 1; m <= 8; m <<= 1) {
#pragma unroll
      for (int i = 0; i < 4; ++i) p4[i] += __shfl_xor(p4[i], m, 64);
    }
    int rr[4];
#pragma unroll
    for (int i = 0; i < 4; ++i) rr[i] = __shfl(r_v, g * 4 + i, 64);
    if (c15 == 0) {
#pragma unroll
      for (int i = 0; i < 4; ++i) {
        f32x4 cd = *reinterpret_cast<const f32x4*>(mbuf + (g * 4 + i) * 136 + 128);
        float fac = rsqrtf(cd[3] + 1e-8f) * tanhf(p4[i]);
        atomicAdd(&x_acc[rr[i] * 4 + 0], cd[0] * fac);
        atomicAdd(&x_acc[rr[i] * 4 + 1], cd[1] * fac);
        atomicAdd(&x_acc[rr[i] * 4 + 2], cd[2] * fac);
      }
    }
  }
}

// ---------------- gather: m_i[n] (bf16) = sum of contiguous m_ij slot rows ----------------
template <int ACC>
__global__ __launch_bounds__(256)
void k_gather(const u16* __restrict__ m_ij, const int* __restrict__ rp,
              u16* __restrict__ m_i) {
  const int tid = threadIdx.x, w = tid >> 6, lane = tid & 63;
  const int grp = lane >> 4, c16 = lane & 15;
  int node = blockIdx.x * 4 + w;                 // 12500*4 == 50000
  int beg = rp[node], end = rp[node + 1];
  float a[8] = {0.f, 0.f, 0.f, 0.f, 0.f, 0.f, 0.f, 0.f};
  for (int j = beg + grp; j < end; j += 4) {
    short8 v = *reinterpret_cast<const short8*>(m_ij + (size_t)j * 128 + c16 * 8);
#pragma unroll
    for (int k = 0; k < 8; ++k) a[k] += bf2f((u16)v[k]);
  }
#pragma unroll
  for (int k = 0; k < 8; ++k) {
    a[k] += __shfl_xor(a[k], 16, 64);
    a[k] += __shfl_xor(a[k], 32, 64);
  }
  if (grp == 0) {
    u16* dst = m_i + (size_t)node * 128 + c16 * 8;
    if (ACC) {
      short8 o = *reinterpret_cast<const short8*>(dst);
#pragma unroll
      for (int k = 0; k < 8; ++k) a[k] += bf2f((u16)o[k]);
    }
    short8 v;
#pragma unroll
    for (int k = 0; k < 8; ++k) v[k] = (short)f2bf(a[k]);
    *reinterpret_cast<short8*>(dst) = v;
  }
}

// ---------------- node kernel (m_i read as bf16 A-fragments directly) ----------------
__global__ __launch_bounds__(256)
void egnn_node2(const float* __restrict__ h, const u16* __restrict__ m_i,
                const u16* __restrict__ wnf,
                const float* __restrict__ bn1, const float* __restrict__ bn2,
                const float* __restrict__ lng, const float* __restrict__ lnb,
                float* __restrict__ h_out) {
  __shared__ u16 mbuf_all[4][2176];
  const int tid = threadIdx.x, w = tid >> 6, lane = tid & 63;
  const int g = lane >> 4, c15 = lane & 15;
  u16* mbuf = mbuf_all[w];
  const u16* wn1f = wnf;
  const u16* wn2f = wnf + 32768;

  float bn1r[8], bn2r[8], lngr[8], lnbr[8];
#pragma unroll
  for (int t = 0; t < 8; ++t) {
    bn1r[t] = bn1[t * 16 + c15];
    bn2r[t] = bn2[t * 16 + c15];
    lngr[t] = lng[t * 16 + c15];
    lnbr[t] = lnb[t * 16 + c15];
  }

  int wt = blockIdx.x * 4 + w;                   // 782*4 = 3128 >= 3125
  if (wt >= 3125) return;
  int nbase = wt * 16;
  int nr = nbase + c15;
  short8 af[8];
#pragma unroll
  for (int s = 0; s < 4; ++s) {
    const float* p = h + nr * 128 + s * 32 + g * 8;
    af[s] = pack8(*reinterpret_cast<const f32x4*>(p),
                  *reinterpret_cast<const f32x4*>(p + 4));
  }
#pragma unroll
  for (int s = 0; s < 4; ++s)
    af[4 + s] = *reinterpret_cast<const short8*>(m_i + (size_t)nr * 128 + s * 32 + g * 8);
  f32x4 acc[8];
#pragma unroll
  for (int t = 0; t < 8; ++t) acc[t] = (f32x4){0.f, 0.f, 0.f, 0.f};
#pragma unroll
  for (int s = 0; s < 8; ++s) {
#pragma unroll
    for (int t = 0; t < 8; ++t) {
      short8 bf = *reinterpret_cast<const short8*>(wn1f + ((t * 8 + s) * 64 + lane) * 8);
      acc[t] = __builtin_amdgcn_mfma_f32_16x16x32_bf16(af[s], bf, acc[t], 0, 0, 0);
    }
  }
#pragma unroll
  for (int t = 0; t < 8; ++t) {
    int col = t * 16 + c15;
#pragma unroll
    for (int i = 0; i < 4; ++i)
      mbuf[(g * 4 + i) * 136 + col] = f2bf(siluf(acc[t][i] + bn1r[t]));
  }
  short8 a2[4];
#pragma unroll
  for (int s = 0; s < 4; ++s)
    a2[s] = *reinterpret_cast<const short8*>(mbuf + c15 * 136 + s * 32 + g * 8);
  f32x4 acc2[8];
#pragma unroll
  for (int t = 0; t < 8; ++t) acc2[t] = (f32x4){0.f, 0.f, 0.f, 0.f};
#pragma unroll
  for (int s = 0; s < 4; ++s) {
#pragma unroll
    for (int t = 0; t < 8; ++t) {
      short8 bf = *reinterpret_cast<const short8*>(wn2f + ((t * 4 + s) * 64 + lane) * 8);
      acc2[t] = __builtin_amdgcn_mfma_f32_16x16x32_bf16(a2[s], bf, acc2[t], 0, 0, 0);
    }
  }
  float vres[8][4];
  float s1[4] = {0.f, 0.f, 0.f, 0.f}, s2[4] = {0.f, 0.f, 0.f, 0.f};
#pragma unroll
  for (int t = 0; t < 8; ++t)
#pragma unroll
    for (int i = 0; i < 4; ++i) {
      int n = nbase + g * 4 + i;
      float v = acc2[t][i] + bn2r[t] + h[n * 128 + t * 16 + c15];
      vres[t][i] = v; s1[i] += v; s2[i] += v * v;
    }
#pragma unroll
  for (int m = 1; m <= 8; m <<= 1) {
#pragma unroll
    for (int i = 0; i < 4; ++i) {
      s1[i] += __shfl_xor(s1[i], m, 64);
      s2[i] += __shfl_xor(s2[i], m, 64);
    }
  }
  float mu[4], rstd[4];
#pragma unroll
  for (int i = 0; i < 4; ++i) {
    mu[i] = s1[i] * (1.0f / 128.0f);
    float var = s2[i] * (1.0f / 128.0f) - mu[i] * mu[i];
    rstd[i] = rsqrtf(var + 1e-5f);
  }
#pragma unroll
  for (int t = 0; t < 8; ++t)
#pragma unroll
    for (int i = 0; i < 4; ++i) {
      int n = nbase + g * 4 + i;
      h_out[n * 128 + t * 16 + c15] =
          (vres[t][i] - mu[i]) * rstd[i] * lngr[t] + lnbr[t];
    }
}

// ---------------- x_out ----------------
__global__ void egnn_xout(const float* __restrict__ x, const float* __restrict__ x_acc,
                          const int* __restrict__ degs, float* __restrict__ xo) {
  int n = blockIdx.x * 256 + threadIdx.x;
  if (n < N_CNT) {
    float dg = fmaxf((float)(degs[n] + degs[N_CNT + n]), 1.0f);
    xo[n * 3 + 0] = x[n * 3 + 0] + x_acc[n * 4 + 0] / dg;
    xo[n * 3 + 1] = x[n * 3 + 1] + x_acc[n * 4 + 1] / dg;
    xo[n * 3 + 2] = x[n * 3 + 2] + x_acc[n * 4 + 2] / dg;
  }
}

extern "C" void kernel_launch(void* const* d_in, const int* in_sizes, int n_in,
                              void* d_out, int out_size, void* d_ws, size_t ws_size,
                              hipStream_t stream) {
  const float* h     = (const float*)d_in[0];
  const float* x     = (const float*)d_in[1];
  const float* ea    = (const float*)d_in[2];
  const float* we_w1 = (const float*)d_in[3];
  const float* we_b1 = (const float*)d_in[4];
  const float* we_w2 = (const float*)d_in[5];
  const float* we_b2 = (const float*)d_in[6];
  const float* wc_w1 = (const float*)d_in[7];
  const float* wc_b1 = (const float*)d_in[8];
  const float* wc_w2 = (const float*)d_in[9];
  const float* wn_w1 = (const float*)d_in[10];
  const float* wn_b1 = (const float*)d_in[11];
  const float* wn_w2 = (const float*)d_in[12];
  const float* wn_b2 = (const float*)d_in[13];
  const float* ln_g  = (const float*)d_in[14];
  const float* ln_b  = (const float*)d_in[15];
  const int* eidx    = (const int*)d_in[16];
  float* out = (float*)d_out;
  char* ws = (char*)d_ws;

  u16* wef    = (u16*)(ws);                      //     73,728
  u16* w1abf  = (u16*)(ws + 73728);              //     65,536
  u16* wnf    = (u16*)(ws + 139264);             //     98,304
  u16* hp     = (u16*)(ws + 237568);             // 25,600,000
  u16* m_i    = (u16*)(ws + 25837568);           // 12,800,000 (bf16; region oversized)
  float* xacc = (float*)(ws + 51437568);         //    800,000
  int* degs   = (int*)(ws + 52237568);           //    400,000
  int* curs   = (int*)(ws + 52637568);           //    400,000
  int* rps    = (int*)(ws + 53037568);           //    400,016
  int* pos    = (int*)(ws + 53437584);           //  3,200,000
  int* bsum   = (int*)(ws + 56637584);           //        800
  int* boff   = (int*)(ws + 56638384);           //        816
  u16* m_ij   = (u16*)(ws + 56639200);           // 102.4 MB (2-batch) / 204.8 MB (1-batch)

  const bool one = ws_size >= 261439200ULL;      // 56,639,200 + 204,800,000
  const int EB = one ? E_CNT : (E_CNT / 2);

  k_wf<<<464, 256, 0, stream>>>(we_w1, we_w2, wc_w1, wn_w1, wn_w2, wef, w1abf, wnf);

  hipFuncSetAttribute(reinterpret_cast<const void*>(k_hp),
                      hipFuncAttributeMaxDynamicSharedMemorySize, 65536);
  k_hp<<<782, 256, 65536, stream>>>(h, w1abf, we_b1, hp);

  hipMemsetAsync(ws + 51437568, 0, 1600000, stream);   // xacc + degs + curs
  k_deg<<<3125, 256, 0, stream>>>(eidx, degs, EB);
  k_bsum<<<196, 256, 0, stream>>>(degs, bsum);
  k_mid<<<1, 128, 0, stream>>>(bsum, boff, rps, EB, E_CNT - EB);
  k_rp<<<196, 256, 0, stream>>>(degs, boff, rps);
  k_scatter<<<3125, 256, 0, stream>>>(eidx, rps, curs, pos, EB);

  hipFuncSetAttribute(reinterpret_cast<const void*>(egnn_edge4),
                      hipFuncAttributeMaxDynamicSharedMemorySize, 159744);
  if (one) {
    // single batch: 50000 wave-tiles (3125*16 exact), one gather pass
    egnn_edge4<<<256, 1024, 159744, stream>>>(hp, x, ea, eidx, pos, wef,
                                              we_b2, wc_b1, wc_w2, m_ij, xacc,
                                              0, 3125, 50000);
    k_gather<0><<<12500, 256, 0, stream>>>(m_ij, rps, m_i);
  } else {
    // two batches (round-11 proven path, identical values)
    egnn_edge4<<<256, 1024, 159744, stream>>>(hp, x, ea, eidx, pos, wef,
                                              we_b2, wc_b1, wc_w2, m_ij, xacc,
                                              0, 1563, 25000);
    k_gather<0><<<12500, 256, 0, stream>>>(m_ij, rps, m_i);
    egnn_edge4<<<256, 1024, 159744, stream>>>(hp, x, ea, eidx, pos, wef,
                                              we_b2, wc_b1, wc_w2, m_ij, xacc,
                                              EB, 1563, 25000);
    k_gather<1><<<12500, 256, 0, stream>>>(m_ij, rps + (N_CNT + 1), m_i);
  }

  egnn_node2<<<782, 256, 0, stream>>>(h, m_i, wnf, wn_b1, wn_b2, ln_g, ln_b, out);
  egnn_xout<<<196, 256, 0, stream>>>(x, xacc, degs, out + 6400000);
}